// Round 7
// baseline (5889.490 us; speedup 1.0000x reference)
//
#include <hip/hip_runtime.h>
#include <stdint.h>

#define NN 100000
#define NE 500000
#define DD 128
#define NL 8
#define NG 64
#define NA 100
#define DET_PAIRS 65536

typedef unsigned short u16;
typedef unsigned int u32;
typedef __attribute__((ext_vector_type(8))) short short8;
typedef __attribute__((ext_vector_type(4))) float f32x4;

union U4 { uint4 v; u16 s[8]; };

__device__ __forceinline__ float b2f(u16 u){ union{u32 i; float f;} x; x.i=((u32)u)<<16; return x.f; }
__device__ __forceinline__ u16 f2b(float f){ union{float f; u32 i;} x; x.f=f; u32 b=x.i; b += 0x7fffu + ((b>>16)&1u); return (u16)(b>>16); }

__global__ void zero_k(int* __restrict__ p, int n){
  int i = blockIdx.x*256 + threadIdx.x;
  if (i < n) p[i] = 0;
}
__global__ void diag_k(u16* __restrict__ out, int n, float val){
  int i = blockIdx.x*256 + threadIdx.x;
  if (i < n) out[i] = f2b(val);
}

// ---------- dtype detection: fp32 vs bf16 params ----------
__global__ void detect_k(const u16* __restrict__ raw, int* __restrict__ flags){
  int i = blockIdx.x*256 + threadIdx.x;
  int ok = 0;
  if (i < DET_PAIRS){
    u16 v = raw[2*i];
    int e = (v>>7)&0xFF;
    ok = ((e >= 107 && e <= 147) || ((v & 0x7FFFu) == 0)) ? 1 : 0;
  }
  unsigned long long b = __ballot(ok);
  if ((threadIdx.x & 63) == 0) atomicAdd(&flags[2], (int)__popcll(b));
}
__global__ void flagset_k(int* __restrict__ flags){
  if (threadIdx.x==0) flags[0] = (flags[2] < DET_PAIRS/2) ? 1 : 0;
}
__global__ void tobf16_k(const void* __restrict__ in, u16* __restrict__ out, int n,
                         const int* __restrict__ flags){
  int i = blockIdx.x*256 + threadIdx.x;
  if (i >= n) return;
  if (flags[0]) out[i] = f2b(((const float*)in)[i]);
  else          out[i] = ((const u16*)in)[i];
}
// convert + transpose: out[l][n][k] = cast(in[l][k][n])
__global__ void convT_k(const void* __restrict__ in, u16* __restrict__ out, int L, int K, int Nn,
                        const int* __restrict__ flags){
  int id = blockIdx.x*256 + threadIdx.x;
  int tot = L*K*Nn;
  if (id >= tot) return;
  int l = id/(K*Nn); int r = id - l*K*Nn;
  int k = r/Nn; int n = r - k*Nn;
  u16 v;
  if (flags[0]) v = f2b(((const float*)in)[id]);
  else          v = ((const u16*)in)[id];
  out[(size_t)l*K*Nn + (size_t)n*K + k] = v;
}

// ---------- feat = emb_table[x] ----------
__global__ void featinit_k(const int* __restrict__ x, const u16* __restrict__ emb, u16* __restrict__ feat){
  int id = blockIdx.x*256 + threadIdx.x;
  if (id >= NN*16) return;
  int row = id>>4, c8 = (id&15)*8;
  int g = x[row];
  *(uint4*)(feat + (size_t)row*DD + c8) = *(const uint4*)(emb + (size_t)g*DD + c8);
}

// ---------- CSR over dst ----------
__global__ void count_k(const int* __restrict__ dst, int* __restrict__ cnt){
  int e = blockIdx.x*256 + threadIdx.x;
  if (e < NE) atomicAdd(&cnt[dst[e]], 1);
}
__global__ void scan1_k(const int* __restrict__ cnt, int* __restrict__ excl, int* __restrict__ bsum, int n){
  __shared__ int sh[256];
  int t = threadIdx.x, g = blockIdx.x*256 + t;
  int v = (g<n) ? cnt[g] : 0;
  sh[t] = v; __syncthreads();
  for (int d=1; d<256; d<<=1){
    int xv = (t>=d) ? sh[t-d] : 0;
    __syncthreads();
    sh[t] += xv;
    __syncthreads();
  }
  if (g<n) excl[g] = sh[t]-v;
  if (t==255) bsum[blockIdx.x] = sh[255];
}
__global__ void scan2_k(int* __restrict__ bsum, int nb){
  if (threadIdx.x==0 && blockIdx.x==0){
    int a=0;
    for (int i=0;i<nb;i++){ int x=bsum[i]; bsum[i]=a; a+=x; }
  }
}
__global__ void scan3_k(const int* __restrict__ excl, const int* __restrict__ bsum,
                        int* __restrict__ offs, int* __restrict__ cursor, int n, int total){
  int g = blockIdx.x*256 + threadIdx.x;
  if (g < n){ int o = excl[g] + bsum[g>>8]; offs[g]=o; cursor[g]=o; }
  if (g==0) offs[n] = total;
}
__global__ void fill_k(const int* __restrict__ dst, int* __restrict__ cursor, int* __restrict__ perm){
  int e = blockIdx.x*256 + threadIdx.x;
  if (e < NE){ int p = atomicAdd(&cursor[dst[e]], 1); perm[p] = e; }
}
__global__ void make_sorted_k(const int* __restrict__ perm, const int* __restrict__ src,
                              const int* __restrict__ dst, int* __restrict__ srcs, int* __restrict__ dsts){
  int i = blockIdx.x*256 + threadIdx.x;
  if (i < NE){ int ed = perm[i]; srcs[i] = src[ed]; dsts[i] = dst[ed]; }
}

// ---------- E (dst-sorted) init + ebg_s ----------
__global__ void edgeinit_k(const int* __restrict__ perm, const int* __restrict__ flow,
                           const int* __restrict__ pos, const int* __restrict__ blk,
                           const int* __restrict__ srcs, const int* __restrict__ dsts,
                           const int* __restrict__ batch,
                           const u16* __restrict__ flow_emb, const u16* __restrict__ pos_emb,
                           const u16* __restrict__ blk_emb,
                           u16* __restrict__ e, int* __restrict__ ebgs){
  int id = blockIdx.x*256 + threadIdx.x;
  if (id >= NE*16) return;
  int i = id>>4, c8 = (id&15)*8;
  int ed = perm[i];
  int s = srcs[i], d = dsts[i];
  int cross = (blk[s] != blk[d]) ? 1 : 0;
  U4 a,b,c,o;
  a.v = *(const uint4*)(flow_emb + (size_t)flow[ed]*DD + c8);
  b.v = *(const uint4*)(pos_emb  + (size_t)pos[ed]*DD + c8);
  c.v = *(const uint4*)(blk_emb  + (size_t)cross*DD + c8);
  #pragma unroll
  for (int j=0;j<8;j++) o.s[j] = f2b(b2f(a.s[j]) + b2f(b.s[j]) + b2f(c.s[j]));
  *(uint4*)(e + (size_t)i*DD + c8) = o.v;
  if ((id&15)==0) ebgs[i] = batch[s];
}

// ---------- GEMM (K=128): C = (relu)(res + A[gather]@B + g0[gi0] + g1[gi1]) ----------
// LDS granule layout: gid = tile*256 + row16*16 + (kgran ^ row16). Staging writes are
// lane-contiguous (conflict-free); MFMA reads are <=2-way (free).
__global__ __launch_bounds__(256,2) void gemm_k(
    const u16* A, const int* __restrict__ idx,
    const u16* __restrict__ Bt, int Ktot,
    const u16* res, int do_relu,
    const u16* __restrict__ g0, const int* __restrict__ gi0,
    const u16* __restrict__ g1, const int* __restrict__ gi1,
    u16* C, int M)
{
  __shared__ u16 As[128*128];
  __shared__ u16 Bs[128*128];
  int t = threadIdx.x;
  int mbase = blockIdx.x*128;
  int lane = t & 63, w = t>>6;
  int wrow = (w>>1)*64, wcol = (w&1)*64;
  int rl_w = t>>4, gw = t&15;
  #pragma unroll
  for (int i=0;i<8;i++){
    int r = rl_w + 16*i;
    int gm = mbase + r;
    uint4 av = make_uint4(0u,0u,0u,0u);
    if (gm < M){
      size_t grow = idx ? (size_t)idx[gm] : (size_t)gm;
      av = *(const uint4*)(A + grow*DD + gw*8);
    }
    int gid = i*256 + rl_w*16 + (gw ^ rl_w);
    *(uint4*)(As + (size_t)gid*8) = av;
    uint4 bv = *(const uint4*)(Bt + (size_t)r*Ktot + gw*8);
    *(uint4*)(Bs + (size_t)gid*8) = bv;
  }
  __syncthreads();
  int l15 = lane & 15, quad = lane>>4;
  f32x4 acc[4][4];
  #pragma unroll
  for (int mi=0;mi<4;mi++)
    #pragma unroll
    for (int ni=0;ni<4;ni++){ acc[mi][ni][0]=0.f; acc[mi][ni][1]=0.f; acc[mi][ni][2]=0.f; acc[mi][ni][3]=0.f; }
  #pragma unroll
  for (int kk=0;kk<4;kk++){
    int kg = kk*4 + quad;
    short8 af[4], bfr[4];
    #pragma unroll
    for (int mi=0;mi<4;mi++)
      af[mi] = *(const short8*)(As + (size_t)(((wrow>>4)+mi)*256 + l15*16 + (kg ^ l15))*8);
    #pragma unroll
    for (int ni=0;ni<4;ni++)
      bfr[ni] = *(const short8*)(Bs + (size_t)(((wcol>>4)+ni)*256 + l15*16 + (kg ^ l15))*8);
    #pragma unroll
    for (int mi=0;mi<4;mi++)
      #pragma unroll
      for (int ni=0;ni<4;ni++)
        acc[mi][ni] = __builtin_amdgcn_mfma_f32_16x16x32_bf16(af[mi], bfr[ni], acc[mi][ni], 0, 0, 0);
  }
  #pragma unroll
  for (int mi=0;mi<4;mi++){
    #pragma unroll
    for (int r4=0;r4<4;r4++){
      int row = wrow + mi*16 + quad*4 + r4;
      int gm = mbase + row;
      if (gm >= M) continue;
      int s0 = gi0 ? gi0[gm] : 0;
      int s1 = gi1 ? gi1[gm] : 0;
      #pragma unroll
      for (int ni=0;ni<4;ni++){
        int col = wcol + ni*16 + l15;
        float v = acc[mi][ni][r4];
        if (res) v += b2f(res[(size_t)gm*DD + col]);
        if (g0)  v += b2f(g0[(size_t)s0*DD + col]) + b2f(g1[(size_t)s1*DD + col]);
        if (do_relu && v < 0.f) v = 0.f;
        C[(size_t)gm*DD + col] = f2b(v);
      }
    }
  }
}

// ---------- fused: ek = E_tile @ Wek (MFMA), then scores ----------
__global__ __launch_bounds__(256,2) void scores_fused_k(
    const u16* __restrict__ E, const u16* __restrict__ WekT,
    const u16* __restrict__ q, const u16* __restrict__ k,
    const int* __restrict__ srcs, const int* __restrict__ dsts,
    float* __restrict__ sc)
{
  __shared__ u16 As[128*128];
  __shared__ u16 Bs[128*128];
  int t = threadIdx.x;
  int ebase = blockIdx.x*128;
  int lane = t & 63, w = t>>6;
  int wrow = (w>>1)*64, wcol = (w&1)*64;
  int rl_w = t>>4, gw = t&15;
  #pragma unroll
  for (int i=0;i<8;i++){
    int r = rl_w + 16*i;
    int gm = ebase + r;
    uint4 av = make_uint4(0u,0u,0u,0u);
    if (gm < NE) av = *(const uint4*)(E + (size_t)gm*DD + gw*8);
    int gid = i*256 + rl_w*16 + (gw ^ rl_w);
    *(uint4*)(As + (size_t)gid*8) = av;
    uint4 bv = *(const uint4*)(WekT + (size_t)r*DD + gw*8);
    *(uint4*)(Bs + (size_t)gid*8) = bv;
  }
  __syncthreads();
  int l15 = lane & 15, quad = lane>>4;
  f32x4 acc[4][4];
  #pragma unroll
  for (int mi=0;mi<4;mi++)
    #pragma unroll
    for (int ni=0;ni<4;ni++){ acc[mi][ni][0]=0.f; acc[mi][ni][1]=0.f; acc[mi][ni][2]=0.f; acc[mi][ni][3]=0.f; }
  #pragma unroll
  for (int kk=0;kk<4;kk++){
    int kg = kk*4 + quad;
    short8 af[4], bfr[4];
    #pragma unroll
    for (int mi=0;mi<4;mi++)
      af[mi] = *(const short8*)(As + (size_t)(((wrow>>4)+mi)*256 + l15*16 + (kg ^ l15))*8);
    #pragma unroll
    for (int ni=0;ni<4;ni++)
      bfr[ni] = *(const short8*)(Bs + (size_t)(((wcol>>4)+ni)*256 + l15*16 + (kg ^ l15))*8);
    #pragma unroll
    for (int mi=0;mi<4;mi++)
      #pragma unroll
      for (int ni=0;ni<4;ni++)
        acc[mi][ni] = __builtin_amdgcn_mfma_f32_16x16x32_bf16(af[mi], bfr[ni], acc[mi][ni], 0, 0, 0);
  }
  __syncthreads();
  #pragma unroll
  for (int mi=0;mi<4;mi++){
    #pragma unroll
    for (int r4=0;r4<4;r4++){
      int row = wrow + mi*16 + quad*4 + r4;
      #pragma unroll
      for (int ni=0;ni<4;ni++){
        int col = wcol + ni*16 + l15;
        As[row*128 + ((((col>>3) ^ (row&15))<<3)) + (col&7)] = f2b(acc[mi][ni][r4]);
      }
    }
  }
  __syncthreads();
  const float scale = 0.17677669529663689f;
  for (int pid = t; pid < 512; pid += 256){
    int le = pid>>2, h = pid&3;
    int e = ebase + le;
    if (e >= NE) continue;
    int s = srcs[e], d = dsts[e];
    float dot = 0.f;
    #pragma unroll
    for (int j4=0;j4<4;j4++){
      int off = h*32 + j4*8;
      U4 qv, kv, ev;
      qv.v = *(const uint4*)(q + (size_t)d*DD + off);
      kv.v = *(const uint4*)(k + (size_t)s*DD + off);
      ev.v = *(const uint4*)(As + le*128 + ((((h*4+j4) ^ (le&15))<<3)));
      #pragma unroll
      for (int j=0;j<8;j++) dot += b2f(qv.s[j]) * (b2f(kv.s[j]) + b2f(ev.s[j]));
    }
    sc[(size_t)e*4 + h] = dot * scale;
  }
}

// ---------- per-node softmax + aggregation over sorted CSR ----------
__global__ __launch_bounds__(256,2) void nodeagg_k(
    const float* __restrict__ sc, const u16* __restrict__ v,
    const u16* __restrict__ E, const int* __restrict__ srcs,
    const int* __restrict__ offs, const u16* __restrict__ WevL,
    u16* __restrict__ agg)
{
  __shared__ float sh[16*4*129];
  int t = threadIdx.x;
  int node = blockIdx.x*16 + (t>>4);
  int sub = t & 15, h = sub>>2, p4 = sub&3;
  float uh[32];
  #pragma unroll
  for (int j=0;j<32;j++) uh[j]=0.f;
  float accv[8] = {0.f,0.f,0.f,0.f,0.f,0.f,0.f,0.f};
  int beg = 0, end = 0;
  if (node < NN){ beg = offs[node]; end = offs[node+1]; }
  float m = -1e30f, den = 0.f;
  for (int i=beg;i<end;i++){
    float s = sc[(size_t)i*4 + h];
    float mn = fmaxf(m, s);
    den = den*__expf(m-mn) + __expf(s-mn);
    m = mn;
  }
  float inv = 1.0f/(den + 1e-16f);
  int offv = h*32 + p4*8;
  for (int i=beg;i<end;i++){
    float a = __expf(sc[(size_t)i*4 + h] - m)*inv;
    U4 vv; vv.v = *(const uint4*)(v + (size_t)srcs[i]*DD + offv);
    #pragma unroll
    for (int j=0;j<8;j++) accv[j] += a*b2f(vv.s[j]);
    const u16* er = E + (size_t)i*DD + p4*32;
    #pragma unroll
    for (int qq=0;qq<4;qq++){
      U4 ee; ee.v = *(const uint4*)(er + qq*8);
      #pragma unroll
      for (int j=0;j<8;j++) uh[qq*8+j] += a*b2f(ee.s[j]);
    }
  }
  int base = ((t>>4)*4 + h)*129;
  #pragma unroll
  for (int j=0;j<32;j++) sh[base + p4*32 + j] = uh[j];
  __syncthreads();
  if (node >= NN) return;
  float o8[8];
  #pragma unroll
  for (int j=0;j<8;j++) o8[j] = accv[j];
  for (int kk=0;kk<128;kk+=4){
    float u0 = sh[base+kk], u1 = sh[base+kk+1], u2 = sh[base+kk+2], u3 = sh[base+kk+3];
    U4 w0,w1,w2,w3;
    w0.v = *(const uint4*)(WevL + (size_t)kk*DD + offv);
    w1.v = *(const uint4*)(WevL + (size_t)(kk+1)*DD + offv);
    w2.v = *(const uint4*)(WevL + (size_t)(kk+2)*DD + offv);
    w3.v = *(const uint4*)(WevL + (size_t)(kk+3)*DD + offv);
    #pragma unroll
    for (int j=0;j<8;j++)
      o8[j] += u0*b2f(w0.s[j]) + u1*b2f(w1.s[j]) + u2*b2f(w2.s[j]) + u3*b2f(w3.s[j]);
  }
  U4 o;
  #pragma unroll
  for (int j=0;j<8;j++) o.s[j] = f2b(o8[j]);
  *(uint4*)(agg + (size_t)node*DD + offv) = o.v;
}

// ---------- pooling: counting sort by graph, then segmented register sums ----------
__global__ void hist_k(const int* __restrict__ gid, const int* __restrict__ mask, int n,
                       int* __restrict__ hist){
  __shared__ int lh[NG];
  int t = threadIdx.x;
  if (t < NG) lh[t]=0;
  __syncthreads();
  int i = blockIdx.x*256 + t;
  if (i < n && (!mask || mask[i]==0)) atomicAdd(&lh[gid[i]], 1);
  __syncthreads();
  if (t < NG && lh[t]) atomicAdd(&hist[t], lh[t]);
}
__global__ void scan64_k(const int* __restrict__ hist, int* __restrict__ base, int* __restrict__ cur){
  if (threadIdx.x==0){
    int a=0;
    for (int g=0; g<NG; g++){ base[g]=a; cur[g]=a; a+=hist[g]; }
    base[NG]=a;
  }
}
__global__ void fillperm_k(const int* __restrict__ gid, const int* __restrict__ mask, int n,
                           int* __restrict__ cur, int* __restrict__ operm){
  __shared__ int lh[NG];
  __shared__ int lb[NG];
  int t = threadIdx.x;
  if (t < NG) lh[t]=0;
  __syncthreads();
  int i = blockIdx.x*256 + t;
  int g=-1, r=0;
  if (i < n && (!mask || mask[i]==0)){ g = gid[i]; r = atomicAdd(&lh[g], 1); }
  __syncthreads();
  if (t < NG && lh[t]) lb[t] = atomicAdd(&cur[t], lh[t]);
  __syncthreads();
  if (g >= 0) operm[lb[g] + r] = i;
}
__global__ __launch_bounds__(256,4) void poolsum_k(
    const u16* __restrict__ feat, const int* __restrict__ operm,
    const int* __restrict__ base, int chunks, float* __restrict__ outsum)
{
  __shared__ float sh[16*128];
  int g = blockIdx.x / chunks, c = blockIdx.x % chunks;
  int beg = base[g], end = base[g+1];
  int len = end - beg;
  int cb = beg + (int)(((long long)len*c)/chunks);
  int ce = beg + (int)(((long long)len*(c+1))/chunks);
  int t = threadIdx.x, grp = t>>4, sub = t&15;
  float acc[8] = {0.f,0.f,0.f,0.f,0.f,0.f,0.f,0.f};
  for (int i = cb+grp; i < ce; i += 16){
    int r = operm[i];
    U4 fv; fv.v = *(const uint4*)(feat + (size_t)r*DD + sub*8);
    #pragma unroll
    for (int j=0;j<8;j++) acc[j] += b2f(fv.s[j]);
  }
  #pragma unroll
  for (int j=0;j<8;j++) sh[grp*128 + sub*8 + j] = acc[j];
  __syncthreads();
  if (t < 128){
    float s = 0.f;
    #pragma unroll
    for (int r=0;r<16;r++) s += sh[r*128 + t];
    if (s != 0.f) atomicAdd(&outsum[g*DD + t], s);
  }
}

__global__ void ganorm_k(const float* __restrict__ gsum, const int* __restrict__ ncnt,
                         const float* __restrict__ esum, const int* __restrict__ ecnt,
                         float* __restrict__ ga){
  int id = blockIdx.x*256 + threadIdx.x;
  if (id >= NG*256) return;
  int g = id>>8, c = id&255;
  float v;
  if (c < 128) v = gsum[g*DD + c] / fmaxf((float)ncnt[g], 1.f);
  else         v = esum[g*DD + (c-128)] / fmaxf((float)ecnt[g], 1.f);
  ga[(size_t)g*256 + c] = v;
}

__global__ void mlp1_k(const float* __restrict__ ga, const u16* __restrict__ QW1,
                       const u16* __restrict__ Qb1, float* __restrict__ h){
  int o = blockIdx.x*256 + threadIdx.x;
  if (o >= NG*DD) return;
  int g = o>>7, j = o&127;
  float s = b2f(Qb1[j]);
  #pragma unroll 4
  for (int kq=0;kq<256;kq++) s += ga[(size_t)g*256 + kq] * b2f(QW1[(size_t)kq*DD + j]);
  h[o] = fmaxf(s, 0.f);
}

__global__ __launch_bounds__(128) void mlp2_k(const float* __restrict__ h, const u16* __restrict__ QW2,
                       const u16* __restrict__ Qb2, void* __restrict__ out, const int* __restrict__ flags){
  __shared__ float lsh[NA];
  __shared__ float red[128];
  int g = blockIdx.x, t = threadIdx.x;
  float s = -1e30f;
  if (t < NA){
    float acc = b2f(Qb2[t]);
    #pragma unroll 4
    for (int kq=0;kq<DD;kq++) acc += h[(size_t)g*DD + kq] * b2f(QW2[(size_t)kq*NA + t]);
    lsh[t] = acc; s = acc;
  }
  red[t] = s; __syncthreads();
  for (int d=64; d>0; d>>=1){ if (t<d) red[t] = fmaxf(red[t], red[t+d]); __syncthreads(); }
  float m = red[0]; __syncthreads();
  float ex = (t < NA) ? __expf(lsh[t]-m) : 0.f;
  red[t] = ex; __syncthreads();
  for (int d=64; d>0; d>>=1){ if (t<d) red[t] += red[t+d]; __syncthreads(); }
  float lse = m + __logf(red[0]);
  if (t < NA){
    float r = lsh[t]-lse;
    if (flags[0]) ((float*)out)[(size_t)g*NA + t] = r;
    else          ((u16*)out)[(size_t)g*NA + t]  = f2b(r);
  }
}

extern "C" void kernel_launch(void* const* d_in, const int* in_sizes, int n_in,
                              void* d_out, int out_size, void* d_ws, size_t ws_size,
                              hipStream_t stream) {
  (void)in_sizes; (void)n_in;
  const int* x      = (const int*)d_in[0];
  const int* ntype  = (const int*)d_in[1];
  const int* batch  = (const int*)d_in[2];
  const int* eidx   = (const int*)d_in[3];
  const int* src    = eidx;
  const int* dstp   = eidx + NE;
  const int* flow   = (const int*)d_in[4];
  const int* pos    = (const int*)d_in[5];
  const int* blk    = (const int*)d_in[6];

  char* p = (char*)d_ws;
  auto alloc = [&](size_t bytes)->char* {
    char* r = p; p += (bytes + 255) & ~(size_t)255; return r;
  };
  u16* embB  = (u16*)alloc((size_t)8192*DD*2);
  u16* flowB = (u16*)alloc(8*DD*2);
  u16* posB  = (u16*)alloc(64*DD*2);
  u16* blkB  = (u16*)alloc(2*DD*2);
  const size_t WSZb = (size_t)NL*DD*DD*2;
  u16* WevB = (u16*)alloc(WSZb);
  u16* QW1B = (u16*)alloc((size_t)256*DD*2);
  u16* Qb1B = (u16*)alloc(DD*2);
  u16* QW2B = (u16*)alloc((size_t)DD*NA*2);
  u16* Qb2B = (u16*)alloc(NA*2);
  u16* WqT  = (u16*)alloc(WSZb);
  u16* WkT  = (u16*)alloc(WSZb);
  u16* WvT  = (u16*)alloc(WSZb);
  u16* WekT = (u16*)alloc(WSZb);
  u16* WoT  = (u16*)alloc(WSZb);
  u16* WeuT = (u16*)alloc((size_t)NL*DD*384*2);
  const size_t NB = (size_t)NN*DD*2;
  u16* A  = (u16*)alloc(NB);
  u16* QB = (u16*)alloc(NB);
  u16* KB = (u16*)alloc(NB);     // k, then v, then P0
  u16* P1 = (u16*)alloc(NB);     // P1 during layers; aliases init/pool int arrays
  const size_t EB = (size_t)NE*DD*2;
  u16* E = (u16*)alloc(EB);
  float* scores = (float*)alloc((size_t)NE*4*4);
  int* srcs   = (int*)alloc((size_t)NE*4);
  int* dsts   = (int*)alloc((size_t)NE*4);
  int* ebgs   = (int*)alloc((size_t)NE*4);
  int* offs   = (int*)alloc((size_t)(NN+1)*4);
  float* gsum = (float*)alloc((size_t)NG*DD*4);
  float* esum = (float*)alloc((size_t)NG*DD*4);
  float* ga = (float*)alloc((size_t)NG*256*4);
  float* h  = (float*)alloc((size_t)NG*DD*4);
  int* flags = (int*)alloc(16);   // [0]=isf32 [2]=detect count

  // sub-allocations inside the P1 region (init-only / pool-only lifetimes):
  char* q = (char*)P1;
  auto suballoc = [&](size_t bytes)->char* {
    char* r = q; q += (bytes + 255) & ~(size_t)255; return r;
  };
  int* perm   = (int*)suballoc((size_t)NE*4);     // init-only
  int* cnt    = (int*)suballoc((size_t)NN*4);     // init-only
  int* excl   = (int*)suballoc((size_t)NN*4);     // init-only
  int* bsum   = (int*)suballoc(1024*4);           // init-only
  int* cursor = (int*)suballoc((size_t)NN*4);     // init-only
  int* eperm  = (int*)suballoc((size_t)NE*4);     // pool-only
  int* nperm  = (int*)suballoc((size_t)NN*4);     // pool-only
  int* ehist  = (int*)suballoc(NG*4);
  int* ebase  = (int*)suballoc((NG+1)*4);
  int* ecur   = (int*)suballoc(NG*4);
  int* nhist  = (int*)suballoc(NG*4);
  int* nbase  = (int*)suballoc((NG+1)*4);
  int* ncur   = (int*)suballoc(NG*4);
  // (total suballoc ~9 MB < 25.6 MB region)

  size_t needed = (size_t)(p - (char*)d_ws);
  if (needed > ws_size){
    diag_k<<<(out_size+255)/256,256,0,stream>>>((u16*)d_out, out_size, (float)(ws_size>>20));
    return;
  }

  // --- dtype detection + param conversion (+fused transpose) ---
  zero_k<<<1,256,0,stream>>>(flags, 4);
  detect_k<<<(DET_PAIRS+255)/256,256,0,stream>>>((const u16*)d_in[8], flags);
  flagset_k<<<1,64,0,stream>>>(flags);
  auto conv = [&](int idx, u16* dst, int n){
    tobf16_k<<<(n+255)/256,256,0,stream>>>(d_in[idx], dst, n, flags);
  };
  auto convT = [&](int idx, u16* dst, int L, int K, int Nc){
    int n = L*K*Nc;
    convT_k<<<(n+255)/256,256,0,stream>>>(d_in[idx], dst, L, K, Nc, flags);
  };
  conv(8,  embB,  8192*DD);
  conv(9,  flowB, 8*DD);
  conv(10, posB,  64*DD);
  conv(11, blkB,  2*DD);
  convT(12, WqT,  NL, DD, DD);
  convT(13, WkT,  NL, DD, DD);
  convT(14, WvT,  NL, DD, DD);
  convT(15, WekT, NL, DD, DD);
  conv(16, WevB, NL*DD*DD);
  convT(17, WoT,  NL, DD, DD);
  convT(18, WeuT, NL, 384, DD);
  conv(19, QW1B, 256*DD);
  conv(20, Qb1B, DD);
  conv(21, QW2B, DD*NA);
  conv(22, Qb2B, NA);

  // --- CSR over dst, sorted edge arrays, init ---
  zero_k<<<(NN+255)/256,256,0,stream>>>(cnt, NN);
  count_k<<<(NE+255)/256,256,0,stream>>>(dstp, cnt);
  int nb = (NN+255)/256;
  scan1_k<<<nb,256,0,stream>>>(cnt, excl, bsum, NN);
  scan2_k<<<1,64,0,stream>>>(bsum, nb);
  scan3_k<<<nb,256,0,stream>>>(excl, bsum, offs, cursor, NN, NE);
  fill_k<<<(NE+255)/256,256,0,stream>>>(dstp, cursor, perm);
  make_sorted_k<<<(NE+255)/256,256,0,stream>>>(perm, src, dstp, srcs, dsts);
  featinit_k<<<(NN*16+255)/256,256,0,stream>>>(x, embB, A);
  edgeinit_k<<<(NE*16+255)/256,256,0,stream>>>(perm, flow, pos, blk, srcs, dsts, batch,
                                               flowB, posB, blkB, E, ebgs);

  // --- layers ---
  dim3 gN((NN+127)/128), gE((NE+127)/128);
  for (int l=0; l<NL; l++){
    const u16* wq  = WqT  + (size_t)l*DD*DD;
    const u16* wk  = WkT  + (size_t)l*DD*DD;
    const u16* wv  = WvT  + (size_t)l*DD*DD;
    const u16* wek = WekT + (size_t)l*DD*DD;
    const u16* wo  = WoT  + (size_t)l*DD*DD;
    const u16* wevL= WevB + (size_t)l*DD*DD;
    const u16* weu = WeuT + (size_t)l*DD*384;

    gemm_k<<<gN,256,0,stream>>>(A,nullptr, wq,128,  nullptr,0, nullptr,nullptr,nullptr,nullptr, QB, NN);
    gemm_k<<<gN,256,0,stream>>>(A,nullptr, wk,128,  nullptr,0, nullptr,nullptr,nullptr,nullptr, KB, NN);
    scores_fused_k<<<gE,256,0,stream>>>(E, wek, QB, KB, srcs, dsts, scores);
    gemm_k<<<gN,256,0,stream>>>(A,nullptr, wv,128,  nullptr,0, nullptr,nullptr,nullptr,nullptr, KB, NN);
    nodeagg_k<<<(NN+15)/16,256,0,stream>>>(scores, KB, E, srcs, offs, wevL, QB);
    // P0 = A @ Weu[0:128]  (v dead -> KB), P1 = A @ Weu[128:256]
    gemm_k<<<gN,256,0,stream>>>(A,nullptr, weu,384,      nullptr,0, nullptr,nullptr,nullptr,nullptr, KB, NN);
    gemm_k<<<gN,256,0,stream>>>(A,nullptr, weu+128,384,  nullptr,0, nullptr,nullptr,nullptr,nullptr, P1, NN);
    // E = relu(E + E@Weu[256:384] + P0[src] + P1[dst])
    gemm_k<<<gE,256,0,stream>>>(E,nullptr, weu+256,384,  E,1, KB,srcs, P1,dsts, E, NE);
    // A = relu(A + agg @ Wo)
    gemm_k<<<gN,256,0,stream>>>(QB,nullptr, wo,128,  A,1, nullptr,nullptr,nullptr,nullptr, A, NN);
  }

  // --- pooling: counting sort by graph + segmented sums ---
  zero_k<<<1,256,0,stream>>>(ehist, NG);
  zero_k<<<1,256,0,stream>>>(nhist, NG);
  zero_k<<<(NG*DD+255)/256,256,0,stream>>>((int*)gsum, NG*DD);
  zero_k<<<(NG*DD+255)/256,256,0,stream>>>((int*)esum, NG*DD);
  hist_k<<<(NE+255)/256,256,0,stream>>>(ebgs, nullptr, NE, ehist);
  hist_k<<<(NN+255)/256,256,0,stream>>>(batch, ntype, NN, nhist);
  scan64_k<<<1,64,0,stream>>>(ehist, ebase, ecur);
  scan64_k<<<1,64,0,stream>>>(nhist, nbase, ncur);
  fillperm_k<<<(NE+255)/256,256,0,stream>>>(ebgs, nullptr, NE, ecur, eperm);
  fillperm_k<<<(NN+255)/256,256,0,stream>>>(batch, ntype, NN, ncur, nperm);
  const int ECH = 16, NCH = 4;
  poolsum_k<<<NG*ECH,256,0,stream>>>(E, eperm, ebase, ECH, esum);
  poolsum_k<<<NG*NCH,256,0,stream>>>(A, nperm, nbase, NCH, gsum);
  ganorm_k<<<(NG*256+255)/256,256,0,stream>>>(gsum, nhist, esum, ehist, ga);
  mlp1_k<<<(NG*DD+255)/256,256,0,stream>>>(ga, QW1B, Qb1B, h);
  mlp2_k<<<NG,128,0,stream>>>(h, QW2B, Qb2B, d_out, flags);
}

// Round 8
// 4862.128 us; speedup vs baseline: 1.2113x; 1.2113x over previous
//
#include <hip/hip_runtime.h>
#include <stdint.h>

#define NN 100000
#define NE 500000
#define DD 128
#define NL 8
#define NG 64
#define NA 100
#define DET_PAIRS 65536

typedef unsigned short u16;
typedef unsigned int u32;
typedef __attribute__((ext_vector_type(8))) short short8;
typedef __attribute__((ext_vector_type(4))) float f32x4;

union U4 { uint4 v; u16 s[8]; };

__device__ __forceinline__ float b2f(u16 u){ union{u32 i; float f;} x; x.i=((u32)u)<<16; return x.f; }
__device__ __forceinline__ u16 f2b(float f){ union{float f; u32 i;} x; x.f=f; u32 b=x.i; b += 0x7fffu + ((b>>16)&1u); return (u16)(b>>16); }

__global__ void zero_k(int* __restrict__ p, int n){
  int i = blockIdx.x*256 + threadIdx.x;
  if (i < n) p[i] = 0;
}
__global__ void diag_k(u16* __restrict__ out, int n, float val){
  int i = blockIdx.x*256 + threadIdx.x;
  if (i < n) out[i] = f2b(val);
}

// ---------- dtype detection: fp32 vs bf16 params ----------
__global__ void detect_k(const u16* __restrict__ raw, int* __restrict__ flags){
  int i = blockIdx.x*256 + threadIdx.x;
  int ok = 0;
  if (i < DET_PAIRS){
    u16 v = raw[2*i];
    int e = (v>>7)&0xFF;
    ok = ((e >= 107 && e <= 147) || ((v & 0x7FFFu) == 0)) ? 1 : 0;
  }
  unsigned long long b = __ballot(ok);
  if ((threadIdx.x & 63) == 0) atomicAdd(&flags[2], (int)__popcll(b));
}
__global__ void flagset_k(int* __restrict__ flags){
  if (threadIdx.x==0) flags[0] = (flags[2] < DET_PAIRS/2) ? 1 : 0;
}
__global__ void tobf16_k(const void* __restrict__ in, u16* __restrict__ out, int n,
                         const int* __restrict__ flags){
  int i = blockIdx.x*256 + threadIdx.x;
  if (i >= n) return;
  if (flags[0]) out[i] = f2b(((const float*)in)[i]);
  else          out[i] = ((const u16*)in)[i];
}
// convert + transpose: out[l][n][k] = cast(in[l][k][n])
__global__ void convT_k(const void* __restrict__ in, u16* __restrict__ out, int L, int K, int Nn,
                        const int* __restrict__ flags){
  int id = blockIdx.x*256 + threadIdx.x;
  int tot = L*K*Nn;
  if (id >= tot) return;
  int l = id/(K*Nn); int r = id - l*K*Nn;
  int k = r/Nn; int n = r - k*Nn;
  u16 v;
  if (flags[0]) v = f2b(((const float*)in)[id]);
  else          v = ((const u16*)in)[id];
  out[(size_t)l*K*Nn + (size_t)n*K + k] = v;
}

// ---------- feat = emb_table[x] ----------
__global__ void featinit_k(const int* __restrict__ x, const u16* __restrict__ emb, u16* __restrict__ feat){
  int id = blockIdx.x*256 + threadIdx.x;
  if (id >= NN*16) return;
  int row = id>>4, c8 = (id&15)*8;
  int g = x[row];
  *(uint4*)(feat + (size_t)row*DD + c8) = *(const uint4*)(emb + (size_t)g*DD + c8);
}

// ---------- CSR over dst ----------
__global__ void count_k(const int* __restrict__ dst, int* __restrict__ cnt){
  int e = blockIdx.x*256 + threadIdx.x;
  if (e < NE) atomicAdd(&cnt[dst[e]], 1);
}
__global__ void scan1_k(const int* __restrict__ cnt, int* __restrict__ excl, int* __restrict__ bsum, int n){
  __shared__ int sh[256];
  int t = threadIdx.x, g = blockIdx.x*256 + t;
  int v = (g<n) ? cnt[g] : 0;
  sh[t] = v; __syncthreads();
  for (int d=1; d<256; d<<=1){
    int xv = (t>=d) ? sh[t-d] : 0;
    __syncthreads();
    sh[t] += xv;
    __syncthreads();
  }
  if (g<n) excl[g] = sh[t]-v;
  if (t==255) bsum[blockIdx.x] = sh[255];
}
__global__ void scan2_k(int* __restrict__ bsum, int nb){
  if (threadIdx.x==0 && blockIdx.x==0){
    int a=0;
    for (int i=0;i<nb;i++){ int x=bsum[i]; bsum[i]=a; a+=x; }
  }
}
__global__ void scan3_k(const int* __restrict__ excl, const int* __restrict__ bsum,
                        int* __restrict__ offs, int* __restrict__ cursor, int n, int total){
  int g = blockIdx.x*256 + threadIdx.x;
  if (g < n){ int o = excl[g] + bsum[g>>8]; offs[g]=o; cursor[g]=o; }
  if (g==0) offs[n] = total;
}
__global__ void fill_k(const int* __restrict__ dst, int* __restrict__ cursor, int* __restrict__ perm){
  int e = blockIdx.x*256 + threadIdx.x;
  if (e < NE){ int p = atomicAdd(&cursor[dst[e]], 1); perm[p] = e; }
}
__global__ void make_sorted_k(const int* __restrict__ perm, const int* __restrict__ src,
                              const int* __restrict__ dst, int* __restrict__ srcs, int* __restrict__ dsts){
  int i = blockIdx.x*256 + threadIdx.x;
  if (i < NE){ int ed = perm[i]; srcs[i] = src[ed]; dsts[i] = dst[ed]; }
}

// ---------- E (dst-sorted) init + ebg_s ----------
__global__ void edgeinit_k(const int* __restrict__ perm, const int* __restrict__ flow,
                           const int* __restrict__ pos, const int* __restrict__ blk,
                           const int* __restrict__ srcs, const int* __restrict__ dsts,
                           const int* __restrict__ batch,
                           const u16* __restrict__ flow_emb, const u16* __restrict__ pos_emb,
                           const u16* __restrict__ blk_emb,
                           u16* __restrict__ e, int* __restrict__ ebgs){
  int id = blockIdx.x*256 + threadIdx.x;
  if (id >= NE*16) return;
  int i = id>>4, c8 = (id&15)*8;
  int ed = perm[i];
  int s = srcs[i], d = dsts[i];
  int cross = (blk[s] != blk[d]) ? 1 : 0;
  U4 a,b,c,o;
  a.v = *(const uint4*)(flow_emb + (size_t)flow[ed]*DD + c8);
  b.v = *(const uint4*)(pos_emb  + (size_t)pos[ed]*DD + c8);
  c.v = *(const uint4*)(blk_emb  + (size_t)cross*DD + c8);
  #pragma unroll
  for (int j=0;j<8;j++) o.s[j] = f2b(b2f(a.s[j]) + b2f(b.s[j]) + b2f(c.s[j]));
  *(uint4*)(e + (size_t)i*DD + c8) = o.v;
  if ((id&15)==0) ebgs[i] = batch[s];
}

// ---------- GEMM: C = (relu)(res + sum_c A_c[gather]@B_c), B-frags direct from L2 ----------
// A staged in 32KB LDS with XOR-granule layout (conflict-free); B read per-fragment
// from global (weight tile is L2-resident and shared by all blocks). 4 blocks/CU.
__global__ __launch_bounds__(256,4) void gemm_k(
    const u16* A0, const int* __restrict__ i0,
    const u16* A1, const int* __restrict__ i1,
    const u16* A2, const int* __restrict__ i2, int nchunks,
    const u16* __restrict__ Bt, int Ktot,
    const u16* res, int do_relu,
    u16* C, int M)
{
  __shared__ u16 As[128*128];
  int t = threadIdx.x;
  int mbase = blockIdx.x*128;
  int lane = t & 63, w = t>>6;
  int wrow = (w>>1)*64, wcol = (w&1)*64;
  int rl_w = t>>4, gw = t&15;
  int l15 = lane & 15, quad = lane>>4;
  f32x4 acc[4][4];
  #pragma unroll
  for (int mi=0;mi<4;mi++)
    #pragma unroll
    for (int ni=0;ni<4;ni++){ acc[mi][ni][0]=0.f; acc[mi][ni][1]=0.f; acc[mi][ni][2]=0.f; acc[mi][ni][3]=0.f; }

  for (int c=0; c<nchunks; c++){
    const u16* A = (c==0)?A0:((c==1)?A1:A2);
    const int* idx = (c==0)?i0:((c==1)?i1:i2);
    if (c > 0) __syncthreads();
    #pragma unroll
    for (int i=0;i<8;i++){
      int gm = mbase + rl_w + 16*i;
      uint4 av = make_uint4(0u,0u,0u,0u);
      if (gm < M){
        size_t grow = idx ? (size_t)idx[gm] : (size_t)gm;
        av = *(const uint4*)(A + grow*DD + gw*8);
      }
      *(uint4*)(As + (size_t)(i*256 + rl_w*16 + (gw ^ rl_w))*8) = av;
    }
    __syncthreads();
    #pragma unroll
    for (int kk=0;kk<4;kk++){
      int kg = kk*4 + quad;
      short8 af[4], bfr[4];
      #pragma unroll
      for (int mi=0;mi<4;mi++)
        af[mi] = *(const short8*)(As + (size_t)(((wrow>>4)+mi)*256 + l15*16 + (kg ^ l15))*8);
      #pragma unroll
      for (int ni=0;ni<4;ni++)
        bfr[ni] = *(const short8*)(Bt + (size_t)(wcol + ni*16 + l15)*Ktot + c*128 + kg*8);
      #pragma unroll
      for (int mi=0;mi<4;mi++)
        #pragma unroll
        for (int ni=0;ni<4;ni++)
          acc[mi][ni] = __builtin_amdgcn_mfma_f32_16x16x32_bf16(af[mi], bfr[ni], acc[mi][ni], 0, 0, 0);
    }
  }

  #pragma unroll
  for (int mi=0;mi<4;mi++){
    #pragma unroll
    for (int r4=0;r4<4;r4++){
      int row = wrow + mi*16 + quad*4 + r4;
      int gm = mbase + row;
      if (gm >= M) continue;
      #pragma unroll
      for (int ni=0;ni<4;ni++){
        int col = wcol + ni*16 + l15;
        float v = acc[mi][ni][r4];
        if (res) v += b2f(res[(size_t)gm*DD + col]);
        if (do_relu && v < 0.f) v = 0.f;
        C[(size_t)gm*DD + col] = f2b(v);
      }
    }
  }
}

// ---------- fused: ek = E_tile @ Wek (MFMA, B direct), then scores ----------
__global__ __launch_bounds__(256,4) void scores_fused_k(
    const u16* __restrict__ E, const u16* __restrict__ WekT,
    const u16* __restrict__ q, const u16* __restrict__ k,
    const int* __restrict__ srcs, const int* __restrict__ dsts,
    float* __restrict__ sc)
{
  __shared__ u16 As[128*128];
  int t = threadIdx.x;
  int ebase = blockIdx.x*128;
  int lane = t & 63, w = t>>6;
  int wrow = (w>>1)*64, wcol = (w&1)*64;
  int rl_w = t>>4, gw = t&15;
  int l15 = lane & 15, quad = lane>>4;
  #pragma unroll
  for (int i=0;i<8;i++){
    int gm = ebase + rl_w + 16*i;
    uint4 av = make_uint4(0u,0u,0u,0u);
    if (gm < NE) av = *(const uint4*)(E + (size_t)gm*DD + gw*8);
    *(uint4*)(As + (size_t)(i*256 + rl_w*16 + (gw ^ rl_w))*8) = av;
  }
  __syncthreads();
  f32x4 acc[4][4];
  #pragma unroll
  for (int mi=0;mi<4;mi++)
    #pragma unroll
    for (int ni=0;ni<4;ni++){ acc[mi][ni][0]=0.f; acc[mi][ni][1]=0.f; acc[mi][ni][2]=0.f; acc[mi][ni][3]=0.f; }
  #pragma unroll
  for (int kk=0;kk<4;kk++){
    int kg = kk*4 + quad;
    short8 af[4], bfr[4];
    #pragma unroll
    for (int mi=0;mi<4;mi++)
      af[mi] = *(const short8*)(As + (size_t)(((wrow>>4)+mi)*256 + l15*16 + (kg ^ l15))*8);
    #pragma unroll
    for (int ni=0;ni<4;ni++)
      bfr[ni] = *(const short8*)(WekT + (size_t)(wcol + ni*16 + l15)*DD + kg*8);
    #pragma unroll
    for (int mi=0;mi<4;mi++)
      #pragma unroll
      for (int ni=0;ni<4;ni++)
        acc[mi][ni] = __builtin_amdgcn_mfma_f32_16x16x32_bf16(af[mi], bfr[ni], acc[mi][ni], 0, 0, 0);
  }
  __syncthreads();
  #pragma unroll
  for (int mi=0;mi<4;mi++){
    #pragma unroll
    for (int r4=0;r4<4;r4++){
      int row = wrow + mi*16 + quad*4 + r4;
      #pragma unroll
      for (int ni=0;ni<4;ni++){
        int col = wcol + ni*16 + l15;
        As[row*128 + ((((col>>3) ^ (row&15))<<3)) + (col&7)] = f2b(acc[mi][ni][r4]);
      }
    }
  }
  __syncthreads();
  const float scale = 0.17677669529663689f;
  for (int pid = t; pid < 512; pid += 256){
    int le = pid>>2, h = pid&3;
    int e = ebase + le;
    if (e >= NE) continue;
    int s = srcs[e], d = dsts[e];
    float dot = 0.f;
    #pragma unroll
    for (int j4=0;j4<4;j4++){
      int off = h*32 + j4*8;
      U4 qv, kv, ev;
      qv.v = *(const uint4*)(q + (size_t)d*DD + off);
      kv.v = *(const uint4*)(k + (size_t)s*DD + off);
      ev.v = *(const uint4*)(As + le*128 + ((((h*4+j4) ^ (le&15))<<3)));
      #pragma unroll
      for (int j=0;j<8;j++) dot += b2f(qv.s[j]) * (b2f(kv.s[j]) + b2f(ev.s[j]));
    }
    sc[(size_t)e*4 + h] = dot * scale;
  }
}

// ---------- per-node softmax + aggregation over sorted CSR ----------
__global__ __launch_bounds__(256,2) void nodeagg_k(
    const float* __restrict__ sc, const u16* __restrict__ v,
    const u16* __restrict__ E, const int* __restrict__ srcs,
    const int* __restrict__ offs, const u16* __restrict__ WevL,
    u16* __restrict__ agg)
{
  __shared__ float sh[16*4*129];
  int t = threadIdx.x;
  int node = blockIdx.x*16 + (t>>4);
  int sub = t & 15, h = sub>>2, p4 = sub&3;
  float uh[32];
  #pragma unroll
  for (int j=0;j<32;j++) uh[j]=0.f;
  float accv[8] = {0.f,0.f,0.f,0.f,0.f,0.f,0.f,0.f};
  int beg = 0, end = 0;
  if (node < NN){ beg = offs[node]; end = offs[node+1]; }
  float m = -1e30f, den = 0.f;
  for (int i=beg;i<end;i++){
    float s = sc[(size_t)i*4 + h];
    float mn = fmaxf(m, s);
    den = den*__expf(m-mn) + __expf(s-mn);
    m = mn;
  }
  float inv = 1.0f/(den + 1e-16f);
  int offv = h*32 + p4*8;
  for (int i=beg;i<end;i++){
    float a = __expf(sc[(size_t)i*4 + h] - m)*inv;
    U4 vv; vv.v = *(const uint4*)(v + (size_t)srcs[i]*DD + offv);
    #pragma unroll
    for (int j=0;j<8;j++) accv[j] += a*b2f(vv.s[j]);
    const u16* er = E + (size_t)i*DD + p4*32;
    #pragma unroll
    for (int qq=0;qq<4;qq++){
      U4 ee; ee.v = *(const uint4*)(er + qq*8);
      #pragma unroll
      for (int j=0;j<8;j++) uh[qq*8+j] += a*b2f(ee.s[j]);
    }
  }
  int base = ((t>>4)*4 + h)*129;
  #pragma unroll
  for (int j=0;j<32;j++) sh[base + p4*32 + j] = uh[j];
  __syncthreads();
  if (node >= NN) return;
  float o8[8];
  #pragma unroll
  for (int j=0;j<8;j++) o8[j] = accv[j];
  for (int kk=0;kk<128;kk+=4){
    float u0 = sh[base+kk], u1 = sh[base+kk+1], u2 = sh[base+kk+2], u3 = sh[base+kk+3];
    U4 w0,w1,w2,w3;
    w0.v = *(const uint4*)(WevL + (size_t)kk*DD + offv);
    w1.v = *(const uint4*)(WevL + (size_t)(kk+1)*DD + offv);
    w2.v = *(const uint4*)(WevL + (size_t)(kk+2)*DD + offv);
    w3.v = *(const uint4*)(WevL + (size_t)(kk+3)*DD + offv);
    #pragma unroll
    for (int j=0;j<8;j++)
      o8[j] += u0*b2f(w0.s[j]) + u1*b2f(w1.s[j]) + u2*b2f(w2.s[j]) + u3*b2f(w3.s[j]);
  }
  U4 o;
  #pragma unroll
  for (int j=0;j<8;j++) o.s[j] = f2b(o8[j]);
  *(uint4*)(agg + (size_t)node*DD + offv) = o.v;
}

// ---------- pooling: counting sort by graph, then segmented register sums ----------
__global__ void hist_k(const int* __restrict__ gid, const int* __restrict__ mask, int n,
                       int* __restrict__ hist){
  __shared__ int lh[NG];
  int t = threadIdx.x;
  if (t < NG) lh[t]=0;
  __syncthreads();
  int i = blockIdx.x*256 + t;
  if (i < n && (!mask || mask[i]==0)) atomicAdd(&lh[gid[i]], 1);
  __syncthreads();
  if (t < NG && lh[t]) atomicAdd(&hist[t], lh[t]);
}
__global__ void scan64_k(const int* __restrict__ hist, int* __restrict__ base, int* __restrict__ cur){
  if (threadIdx.x==0){
    int a=0;
    for (int g=0; g<NG; g++){ base[g]=a; cur[g]=a; a+=hist[g]; }
    base[NG]=a;
  }
}
__global__ void fillperm_k(const int* __restrict__ gid, const int* __restrict__ mask, int n,
                           int* __restrict__ cur, int* __restrict__ operm){
  __shared__ int lh[NG];
  __shared__ int lb[NG];
  int t = threadIdx.x;
  if (t < NG) lh[t]=0;
  __syncthreads();
  int i = blockIdx.x*256 + t;
  int g=-1, r=0;
  if (i < n && (!mask || mask[i]==0)){ g = gid[i]; r = atomicAdd(&lh[g], 1); }
  __syncthreads();
  if (t < NG && lh[t]) lb[t] = atomicAdd(&cur[t], lh[t]);
  __syncthreads();
  if (g >= 0) operm[lb[g] + r] = i;
}
__global__ __launch_bounds__(256,4) void poolsum_k(
    const u16* __restrict__ feat, const int* __restrict__ operm,
    const int* __restrict__ base, int chunks, float* __restrict__ outsum)
{
  __shared__ float sh[16*128];
  int g = blockIdx.x / chunks, c = blockIdx.x % chunks;
  int beg = base[g], end = base[g+1];
  int len = end - beg;
  int cb = beg + (int)(((long long)len*c)/chunks);
  int ce = beg + (int)(((long long)len*(c+1))/chunks);
  int t = threadIdx.x, grp = t>>4, sub = t&15;
  float acc[8] = {0.f,0.f,0.f,0.f,0.f,0.f,0.f,0.f};
  for (int i = cb+grp; i < ce; i += 16){
    int r = operm[i];
    U4 fv; fv.v = *(const uint4*)(feat + (size_t)r*DD + sub*8);
    #pragma unroll
    for (int j=0;j<8;j++) acc[j] += b2f(fv.s[j]);
  }
  #pragma unroll
  for (int j=0;j<8;j++) sh[grp*128 + sub*8 + j] = acc[j];
  __syncthreads();
  if (t < 128){
    float s = 0.f;
    #pragma unroll
    for (int r=0;r<16;r++) s += sh[r*128 + t];
    if (s != 0.f) atomicAdd(&outsum[g*DD + t], s);
  }
}

__global__ void ganorm_k(const float* __restrict__ gsum, const int* __restrict__ ncnt,
                         const float* __restrict__ esum, const int* __restrict__ ecnt,
                         float* __restrict__ ga){
  int id = blockIdx.x*256 + threadIdx.x;
  if (id >= NG*256) return;
  int g = id>>8, c = id&255;
  float v;
  if (c < 128) v = gsum[g*DD + c] / fmaxf((float)ncnt[g], 1.f);
  else         v = esum[g*DD + (c-128)] / fmaxf((float)ecnt[g], 1.f);
  ga[(size_t)g*256 + c] = v;
}

__global__ void mlp1_k(const float* __restrict__ ga, const u16* __restrict__ QW1,
                       const u16* __restrict__ Qb1, float* __restrict__ h){
  int o = blockIdx.x*256 + threadIdx.x;
  if (o >= NG*DD) return;
  int g = o>>7, j = o&127;
  float s = b2f(Qb1[j]);
  #pragma unroll 4
  for (int kq=0;kq<256;kq++) s += ga[(size_t)g*256 + kq] * b2f(QW1[(size_t)kq*DD + j]);
  h[o] = fmaxf(s, 0.f);
}

__global__ __launch_bounds__(128) void mlp2_k(const float* __restrict__ h, const u16* __restrict__ QW2,
                       const u16* __restrict__ Qb2, void* __restrict__ out, const int* __restrict__ flags){
  __shared__ float lsh[NA];
  __shared__ float red[128];
  int g = blockIdx.x, t = threadIdx.x;
  float s = -1e30f;
  if (t < NA){
    float acc = b2f(Qb2[t]);
    #pragma unroll 4
    for (int kq=0;kq<DD;kq++) acc += h[(size_t)g*DD + kq] * b2f(QW2[(size_t)kq*NA + t]);
    lsh[t] = acc; s = acc;
  }
  red[t] = s; __syncthreads();
  for (int d=64; d>0; d>>=1){ if (t<d) red[t] = fmaxf(red[t], red[t+d]); __syncthreads(); }
  float m = red[0]; __syncthreads();
  float ex = (t < NA) ? __expf(lsh[t]-m) : 0.f;
  red[t] = ex; __syncthreads();
  for (int d=64; d>0; d>>=1){ if (t<d) red[t] += red[t+d]; __syncthreads(); }
  float lse = m + __logf(red[0]);
  if (t < NA){
    float r = lsh[t]-lse;
    if (flags[0]) ((float*)out)[(size_t)g*NA + t] = r;
    else          ((u16*)out)[(size_t)g*NA + t]  = f2b(r);
  }
}

extern "C" void kernel_launch(void* const* d_in, const int* in_sizes, int n_in,
                              void* d_out, int out_size, void* d_ws, size_t ws_size,
                              hipStream_t stream) {
  (void)in_sizes; (void)n_in;
  const int* x      = (const int*)d_in[0];
  const int* ntype  = (const int*)d_in[1];
  const int* batch  = (const int*)d_in[2];
  const int* eidx   = (const int*)d_in[3];
  const int* src    = eidx;
  const int* dstp   = eidx + NE;
  const int* flow   = (const int*)d_in[4];
  const int* pos    = (const int*)d_in[5];
  const int* blk    = (const int*)d_in[6];

  char* p = (char*)d_ws;
  auto alloc = [&](size_t bytes)->char* {
    char* r = p; p += (bytes + 255) & ~(size_t)255; return r;
  };
  u16* embB  = (u16*)alloc((size_t)8192*DD*2);
  u16* flowB = (u16*)alloc(8*DD*2);
  u16* posB  = (u16*)alloc(64*DD*2);
  u16* blkB  = (u16*)alloc(2*DD*2);
  const size_t WSZb = (size_t)NL*DD*DD*2;
  u16* WevB = (u16*)alloc(WSZb);
  u16* QW1B = (u16*)alloc((size_t)256*DD*2);
  u16* Qb1B = (u16*)alloc(DD*2);
  u16* QW2B = (u16*)alloc((size_t)DD*NA*2);
  u16* Qb2B = (u16*)alloc(NA*2);
  u16* WqT  = (u16*)alloc(WSZb);
  u16* WkT  = (u16*)alloc(WSZb);
  u16* WvT  = (u16*)alloc(WSZb);
  u16* WekT = (u16*)alloc(WSZb);
  u16* WoT  = (u16*)alloc(WSZb);
  u16* WeuT = (u16*)alloc((size_t)NL*DD*384*2);
  const size_t NB = (size_t)NN*DD*2;
  u16* A  = (u16*)alloc(NB);
  u16* QB = (u16*)alloc(NB);
  u16* KB = (u16*)alloc(NB);     // k, then v
  u16* SCRATCH = (u16*)alloc(NB);  // hosts init-only / pool-only int arrays
  const size_t EB = (size_t)NE*DD*2;
  u16* E = (u16*)alloc(EB);
  float* scores = (float*)alloc((size_t)NE*4*4);
  int* srcs   = (int*)alloc((size_t)NE*4);
  int* dsts   = (int*)alloc((size_t)NE*4);
  int* ebgs   = (int*)alloc((size_t)NE*4);
  int* offs   = (int*)alloc((size_t)(NN+1)*4);
  float* gsum = (float*)alloc((size_t)NG*DD*4);
  float* esum = (float*)alloc((size_t)NG*DD*4);
  float* ga = (float*)alloc((size_t)NG*256*4);
  float* h  = (float*)alloc((size_t)NG*DD*4);
  int* flags = (int*)alloc(16);   // [0]=isf32 [2]=detect count

  // sub-allocations inside SCRATCH (init-only / pool-only lifetimes):
  char* q = (char*)SCRATCH;
  auto suballoc = [&](size_t bytes)->char* {
    char* r = q; q += (bytes + 255) & ~(size_t)255; return r;
  };
  int* perm   = (int*)suballoc((size_t)NE*4);     // init-only
  int* cnt    = (int*)suballoc((size_t)NN*4);     // init-only
  int* excl   = (int*)suballoc((size_t)NN*4);     // init-only
  int* bsum   = (int*)suballoc(1024*4);           // init-only
  int* cursor = (int*)suballoc((size_t)NN*4);     // init-only
  int* eperm  = (int*)suballoc((size_t)NE*4);     // pool-only
  int* nperm  = (int*)suballoc((size_t)NN*4);     // pool-only
  int* ehist  = (int*)suballoc(NG*4);
  int* ebase  = (int*)suballoc((NG+1)*4);
  int* ecur   = (int*)suballoc(NG*4);
  int* nhist  = (int*)suballoc(NG*4);
  int* nbase  = (int*)suballoc((NG+1)*4);
  int* ncur   = (int*)suballoc(NG*4);

  size_t needed = (size_t)(p - (char*)d_ws);
  if (needed > ws_size){
    diag_k<<<(out_size+255)/256,256,0,stream>>>((u16*)d_out, out_size, (float)(ws_size>>20));
    return;
  }

  // --- dtype detection + param conversion (+fused transpose) ---
  zero_k<<<1,256,0,stream>>>(flags, 4);
  detect_k<<<(DET_PAIRS+255)/256,256,0,stream>>>((const u16*)d_in[8], flags);
  flagset_k<<<1,64,0,stream>>>(flags);
  auto conv = [&](int idx, u16* dst, int n){
    tobf16_k<<<(n+255)/256,256,0,stream>>>(d_in[idx], dst, n, flags);
  };
  auto convT = [&](int idx, u16* dst, int L, int K, int Nc){
    int n = L*K*Nc;
    convT_k<<<(n+255)/256,256,0,stream>>>(d_in[idx], dst, L, K, Nc, flags);
  };
  conv(8,  embB,  8192*DD);
  conv(9,  flowB, 8*DD);
  conv(10, posB,  64*DD);
  conv(11, blkB,  2*DD);
  convT(12, WqT,  NL, DD, DD);
  convT(13, WkT,  NL, DD, DD);
  convT(14, WvT,  NL, DD, DD);
  convT(15, WekT, NL, DD, DD);
  conv(16, WevB, NL*DD*DD);
  convT(17, WoT,  NL, DD, DD);
  convT(18, WeuT, NL, 384, DD);
  conv(19, QW1B, 256*DD);
  conv(20, Qb1B, DD);
  conv(21, QW2B, DD*NA);
  conv(22, Qb2B, NA);

  // --- CSR over dst, sorted edge arrays, init ---
  zero_k<<<(NN+255)/256,256,0,stream>>>(cnt, NN);
  count_k<<<(NE+255)/256,256,0,stream>>>(dstp, cnt);
  int nb = (NN+255)/256;
  scan1_k<<<nb,256,0,stream>>>(cnt, excl, bsum, NN);
  scan2_k<<<1,64,0,stream>>>(bsum, nb);
  scan3_k<<<nb,256,0,stream>>>(excl, bsum, offs, cursor, NN, NE);
  fill_k<<<(NE+255)/256,256,0,stream>>>(dstp, cursor, perm);
  make_sorted_k<<<(NE+255)/256,256,0,stream>>>(perm, src, dstp, srcs, dsts);
  featinit_k<<<(NN*16+255)/256,256,0,stream>>>(x, embB, A);
  edgeinit_k<<<(NE*16+255)/256,256,0,stream>>>(perm, flow, pos, blk, srcs, dsts, batch,
                                               flowB, posB, blkB, E, ebgs);

  // --- layers ---
  dim3 gN((NN+127)/128), gE((NE+127)/128);
  for (int l=0; l<NL; l++){
    const u16* wq  = WqT  + (size_t)l*DD*DD;
    const u16* wk  = WkT  + (size_t)l*DD*DD;
    const u16* wv  = WvT  + (size_t)l*DD*DD;
    const u16* wek = WekT + (size_t)l*DD*DD;
    const u16* wo  = WoT  + (size_t)l*DD*DD;
    const u16* wevL= WevB + (size_t)l*DD*DD;
    const u16* weu = WeuT + (size_t)l*DD*384;

    gemm_k<<<gN,256,0,stream>>>(A,nullptr,nullptr,nullptr,nullptr,nullptr,1, wq,128, nullptr,0, QB, NN);
    gemm_k<<<gN,256,0,stream>>>(A,nullptr,nullptr,nullptr,nullptr,nullptr,1, wk,128, nullptr,0, KB, NN);
    scores_fused_k<<<gE,256,0,stream>>>(E, wek, QB, KB, srcs, dsts, scores);
    gemm_k<<<gN,256,0,stream>>>(A,nullptr,nullptr,nullptr,nullptr,nullptr,1, wv,128, nullptr,0, KB, NN);
    nodeagg_k<<<(NN+15)/16,256,0,stream>>>(scores, KB, E, srcs, offs, wevL, QB);
    // E = relu(E + [A[src], A[dst], E] @ Weu)  (3-chunk gather staging, in-place)
    gemm_k<<<gE,256,0,stream>>>(A,srcs, A,dsts, E,nullptr, 3, weu,384, E,1, E, NE);
    // A = relu(A + agg @ Wo)
    gemm_k<<<gN,256,0,stream>>>(QB,nullptr,nullptr,nullptr,nullptr,nullptr,1, wo,128, A,1, A, NN);
  }

  // --- pooling: counting sort by graph + segmented sums ---
  zero_k<<<1,256,0,stream>>>(ehist, NG);
  zero_k<<<1,256,0,stream>>>(nhist, NG);
  zero_k<<<(NG*DD+255)/256,256,0,stream>>>((int*)gsum, NG*DD);
  zero_k<<<(NG*DD+255)/256,256,0,stream>>>((int*)esum, NG*DD);
  hist_k<<<(NE+255)/256,256,0,stream>>>(ebgs, nullptr, NE, ehist);
  hist_k<<<(NN+255)/256,256,0,stream>>>(batch, ntype, NN, nhist);
  scan64_k<<<1,64,0,stream>>>(ehist, ebase, ecur);
  scan64_k<<<1,64,0,stream>>>(nhist, nbase, ncur);
  fillperm_k<<<(NE+255)/256,256,0,stream>>>(ebgs, nullptr, NE, ecur, eperm);
  fillperm_k<<<(NN+255)/256,256,0,stream>>>(batch, ntype, NN, ncur, nperm);
  const int ECH = 16, NCH = 4;
  poolsum_k<<<NG*ECH,256,0,stream>>>(E, eperm, ebase, ECH, esum);
  poolsum_k<<<NG*NCH,256,0,stream>>>(A, nperm, nbase, NCH, gsum);
  ganorm_k<<<(NG*256+255)/256,256,0,stream>>>(gsum, nhist, esum, ehist, ga);
  mlp1_k<<<(NG*DD+255)/256,256,0,stream>>>(ga, QW1B, Qb1B, h);
  mlp2_k<<<NG,128,0,stream>>>(h, QW2B, Qb2B, d_out, flags);
}

// Round 9
// 4681.011 us; speedup vs baseline: 1.2582x; 1.0387x over previous
//
#include <hip/hip_runtime.h>
#include <stdint.h>

#define NN 100000
#define NE 500000
#define DD 128
#define NL 8
#define NG 64
#define NA 100
#define DET_PAIRS 65536

typedef unsigned short u16;
typedef unsigned int u32;
typedef __attribute__((ext_vector_type(8))) short short8;
typedef __attribute__((ext_vector_type(4))) float f32x4;

union U4 { uint4 v; u16 s[8]; };

__device__ __forceinline__ float b2f(u16 u){ union{u32 i; float f;} x; x.i=((u32)u)<<16; return x.f; }
__device__ __forceinline__ u16 f2b(float f){ union{float f; u32 i;} x; x.f=f; u32 b=x.i; b += 0x7fffu + ((b>>16)&1u); return (u16)(b>>16); }

__global__ void zero_k(int* __restrict__ p, int n){
  int i = blockIdx.x*256 + threadIdx.x;
  if (i < n) p[i] = 0;
}
__global__ void diag_k(u16* __restrict__ out, int n, float val){
  int i = blockIdx.x*256 + threadIdx.x;
  if (i < n) out[i] = f2b(val);
}

// ---------- dtype detection: fp32 vs bf16 params ----------
__global__ void detect_k(const u16* __restrict__ raw, int* __restrict__ flags){
  int i = blockIdx.x*256 + threadIdx.x;
  int ok = 0;
  if (i < DET_PAIRS){
    u16 v = raw[2*i];
    int e = (v>>7)&0xFF;
    ok = ((e >= 107 && e <= 147) || ((v & 0x7FFFu) == 0)) ? 1 : 0;
  }
  unsigned long long b = __ballot(ok);
  if ((threadIdx.x & 63) == 0) atomicAdd(&flags[2], (int)__popcll(b));
}
__global__ void flagset_k(int* __restrict__ flags){
  if (threadIdx.x==0) flags[0] = (flags[2] < DET_PAIRS/2) ? 1 : 0;
}
__global__ void tobf16_k(const void* __restrict__ in, u16* __restrict__ out, int n,
                         const int* __restrict__ flags){
  int i = blockIdx.x*256 + threadIdx.x;
  if (i >= n) return;
  if (flags[0]) out[i] = f2b(((const float*)in)[i]);
  else          out[i] = ((const u16*)in)[i];
}
// convert + transpose: out[l][n][k] = cast(in[l][k][n])
__global__ void convT_k(const void* __restrict__ in, u16* __restrict__ out, int L, int K, int Nn,
                        const int* __restrict__ flags){
  int id = blockIdx.x*256 + threadIdx.x;
  int tot = L*K*Nn;
  if (id >= tot) return;
  int l = id/(K*Nn); int r = id - l*K*Nn;
  int k = r/Nn; int n = r - k*Nn;
  u16 v;
  if (flags[0]) v = f2b(((const float*)in)[id]);
  else          v = ((const u16*)in)[id];
  out[(size_t)l*K*Nn + (size_t)n*K + k] = v;
}

// ---------- feat = emb_table[x] ----------
__global__ void featinit_k(const int* __restrict__ x, const u16* __restrict__ emb, u16* __restrict__ feat){
  int id = blockIdx.x*256 + threadIdx.x;
  if (id >= NN*16) return;
  int row = id>>4, c8 = (id&15)*8;
  int g = x[row];
  *(uint4*)(feat + (size_t)row*DD + c8) = *(const uint4*)(emb + (size_t)g*DD + c8);
}

// ---------- CSR over dst ----------
__global__ void count_k(const int* __restrict__ dst, int* __restrict__ cnt){
  int e = blockIdx.x*256 + threadIdx.x;
  if (e < NE) atomicAdd(&cnt[dst[e]], 1);
}
__global__ void scan1_k(const int* __restrict__ cnt, int* __restrict__ excl, int* __restrict__ bsum, int n){
  __shared__ int sh[256];
  int t = threadIdx.x, g = blockIdx.x*256 + t;
  int v = (g<n) ? cnt[g] : 0;
  sh[t] = v; __syncthreads();
  for (int d=1; d<256; d<<=1){
    int xv = (t>=d) ? sh[t-d] : 0;
    __syncthreads();
    sh[t] += xv;
    __syncthreads();
  }
  if (g<n) excl[g] = sh[t]-v;
  if (t==255) bsum[blockIdx.x] = sh[255];
}
__global__ void scan2_k(int* __restrict__ bsum, int nb){
  if (threadIdx.x==0 && blockIdx.x==0){
    int a=0;
    for (int i=0;i<nb;i++){ int x=bsum[i]; bsum[i]=a; a+=x; }
  }
}
__global__ void scan3_k(const int* __restrict__ excl, const int* __restrict__ bsum,
                        int* __restrict__ offs, int* __restrict__ cursor, int n, int total){
  int g = blockIdx.x*256 + threadIdx.x;
  if (g < n){ int o = excl[g] + bsum[g>>8]; offs[g]=o; cursor[g]=o; }
  if (g==0) offs[n] = total;
}
__global__ void fill_k(const int* __restrict__ dst, int* __restrict__ cursor, int* __restrict__ perm){
  int e = blockIdx.x*256 + threadIdx.x;
  if (e < NE){ int p = atomicAdd(&cursor[dst[e]], 1); perm[p] = e; }
}
__global__ void make_sorted_k(const int* __restrict__ perm, const int* __restrict__ src,
                              const int* __restrict__ dst, int* __restrict__ srcs, int* __restrict__ dsts){
  int i = blockIdx.x*256 + threadIdx.x;
  if (i < NE){ int ed = perm[i]; srcs[i] = src[ed]; dsts[i] = dst[ed]; }
}

// ---------- E (dst-sorted) init + ebg_s ----------
__global__ void edgeinit_k(const int* __restrict__ perm, const int* __restrict__ flow,
                           const int* __restrict__ pos, const int* __restrict__ blk,
                           const int* __restrict__ srcs, const int* __restrict__ dsts,
                           const int* __restrict__ batch,
                           const u16* __restrict__ flow_emb, const u16* __restrict__ pos_emb,
                           const u16* __restrict__ blk_emb,
                           u16* __restrict__ e, int* __restrict__ ebgs){
  int id = blockIdx.x*256 + threadIdx.x;
  if (id >= NE*16) return;
  int i = id>>4, c8 = (id&15)*8;
  int ed = perm[i];
  int s = srcs[i], d = dsts[i];
  int cross = (blk[s] != blk[d]) ? 1 : 0;
  U4 a,b,c,o;
  a.v = *(const uint4*)(flow_emb + (size_t)flow[ed]*DD + c8);
  b.v = *(const uint4*)(pos_emb  + (size_t)pos[ed]*DD + c8);
  c.v = *(const uint4*)(blk_emb  + (size_t)cross*DD + c8);
  #pragma unroll
  for (int j=0;j<8;j++) o.s[j] = f2b(b2f(a.s[j]) + b2f(b.s[j]) + b2f(c.s[j]));
  *(uint4*)(e + (size_t)i*DD + c8) = o.v;
  if ((id&15)==0) ebgs[i] = batch[s];
}

// ---------- GEMM: C = (relu)(res + sum_c A_c[gather]@B_c), B-frags direct from L2 ----------
// A staged in 32KB LDS (XOR-granule, conflict-free); B per-fragment from global
// (L2-resident weight tile). Epilogue: acc -> LDS -> fully-coalesced uint4 res/C.
__global__ __launch_bounds__(256,4) void gemm_k(
    const u16* A0, const int* __restrict__ i0,
    const u16* A1, const int* __restrict__ i1,
    const u16* A2, const int* __restrict__ i2, int nchunks,
    const u16* __restrict__ Bt, int Ktot,
    const u16* res, int do_relu,
    u16* C, int M)
{
  __shared__ u16 As[128*128];
  int t = threadIdx.x;
  int mbase = blockIdx.x*128;
  int lane = t & 63, w = t>>6;
  int wrow = (w>>1)*64, wcol = (w&1)*64;
  int rl_w = t>>4, gw = t&15;
  int l15 = lane & 15, quad = lane>>4;
  f32x4 acc[4][4];
  #pragma unroll
  for (int mi=0;mi<4;mi++)
    #pragma unroll
    for (int ni=0;ni<4;ni++){ acc[mi][ni][0]=0.f; acc[mi][ni][1]=0.f; acc[mi][ni][2]=0.f; acc[mi][ni][3]=0.f; }

  for (int c=0; c<nchunks; c++){
    const u16* A = (c==0)?A0:((c==1)?A1:A2);
    const int* idx = (c==0)?i0:((c==1)?i1:i2);
    if (c > 0) __syncthreads();
    #pragma unroll
    for (int i=0;i<8;i++){
      int gm = mbase + rl_w + 16*i;
      uint4 av = make_uint4(0u,0u,0u,0u);
      if (gm < M){
        size_t grow = idx ? (size_t)idx[gm] : (size_t)gm;
        av = *(const uint4*)(A + grow*DD + gw*8);
      }
      *(uint4*)(As + (size_t)(i*256 + rl_w*16 + (gw ^ rl_w))*8) = av;
    }
    __syncthreads();
    #pragma unroll
    for (int kk=0;kk<4;kk++){
      int kg = kk*4 + quad;
      short8 af[4], bfr[4];
      #pragma unroll
      for (int mi=0;mi<4;mi++)
        af[mi] = *(const short8*)(As + (size_t)(((wrow>>4)+mi)*256 + l15*16 + (kg ^ l15))*8);
      #pragma unroll
      for (int ni=0;ni<4;ni++)
        bfr[ni] = *(const short8*)(Bt + (size_t)(wcol + ni*16 + l15)*Ktot + c*128 + kg*8);
      #pragma unroll
      for (int mi=0;mi<4;mi++)
        #pragma unroll
        for (int ni=0;ni<4;ni++)
          acc[mi][ni] = __builtin_amdgcn_mfma_f32_16x16x32_bf16(af[mi], bfr[ni], acc[mi][ni], 0, 0, 0);
    }
  }

  // epilogue: acc -> LDS (swizzled) -> coalesced res-read + C-write
  __syncthreads();
  #pragma unroll
  for (int mi=0;mi<4;mi++){
    #pragma unroll
    for (int r4=0;r4<4;r4++){
      int row = wrow + mi*16 + quad*4 + r4;
      #pragma unroll
      for (int ni=0;ni<4;ni++){
        int col = wcol + ni*16 + l15;
        As[row*128 + ((((col>>3) ^ (row&15))<<3)) + (col&7)] = f2b(acc[mi][ni][r4]);
      }
    }
  }
  __syncthreads();
  #pragma unroll
  for (int i=0;i<8;i++){
    int row = rl_w + 16*i;
    int gm = mbase + row;
    if (gm >= M) continue;
    U4 av; av.v = *(const uint4*)(As + row*128 + ((gw ^ (row&15))<<3));
    float vals[8];
    #pragma unroll
    for (int j=0;j<8;j++) vals[j] = b2f(av.s[j]);
    if (res){
      U4 rv; rv.v = *(const uint4*)(res + (size_t)gm*DD + gw*8);
      #pragma unroll
      for (int j=0;j<8;j++) vals[j] += b2f(rv.s[j]);
    }
    U4 ov;
    #pragma unroll
    for (int j=0;j<8;j++){
      float v = vals[j];
      if (do_relu && v < 0.f) v = 0.f;
      ov.s[j] = f2b(v);
    }
    *(uint4*)(C + (size_t)gm*DD + gw*8) = ov.v;
  }
}

// ---------- fused: ek = E_tile @ Wek (MFMA, B direct), then scores ----------
__global__ __launch_bounds__(256,4) void scores_fused_k(
    const u16* __restrict__ E, const u16* __restrict__ WekT,
    const u16* __restrict__ q, const u16* __restrict__ k,
    const int* __restrict__ srcs, const int* __restrict__ dsts,
    float* __restrict__ sc)
{
  __shared__ u16 As[128*128];
  int t = threadIdx.x;
  int ebase = blockIdx.x*128;
  int lane = t & 63, w = t>>6;
  int wrow = (w>>1)*64, wcol = (w&1)*64;
  int rl_w = t>>4, gw = t&15;
  int l15 = lane & 15, quad = lane>>4;
  #pragma unroll
  for (int i=0;i<8;i++){
    int gm = ebase + rl_w + 16*i;
    uint4 av = make_uint4(0u,0u,0u,0u);
    if (gm < NE) av = *(const uint4*)(E + (size_t)gm*DD + gw*8);
    *(uint4*)(As + (size_t)(i*256 + rl_w*16 + (gw ^ rl_w))*8) = av;
  }
  __syncthreads();
  f32x4 acc[4][4];
  #pragma unroll
  for (int mi=0;mi<4;mi++)
    #pragma unroll
    for (int ni=0;ni<4;ni++){ acc[mi][ni][0]=0.f; acc[mi][ni][1]=0.f; acc[mi][ni][2]=0.f; acc[mi][ni][3]=0.f; }
  #pragma unroll
  for (int kk=0;kk<4;kk++){
    int kg = kk*4 + quad;
    short8 af[4], bfr[4];
    #pragma unroll
    for (int mi=0;mi<4;mi++)
      af[mi] = *(const short8*)(As + (size_t)(((wrow>>4)+mi)*256 + l15*16 + (kg ^ l15))*8);
    #pragma unroll
    for (int ni=0;ni<4;ni++)
      bfr[ni] = *(const short8*)(WekT + (size_t)(wcol + ni*16 + l15)*DD + kg*8);
    #pragma unroll
    for (int mi=0;mi<4;mi++)
      #pragma unroll
      for (int ni=0;ni<4;ni++)
        acc[mi][ni] = __builtin_amdgcn_mfma_f32_16x16x32_bf16(af[mi], bfr[ni], acc[mi][ni], 0, 0, 0);
  }
  __syncthreads();
  #pragma unroll
  for (int mi=0;mi<4;mi++){
    #pragma unroll
    for (int r4=0;r4<4;r4++){
      int row = wrow + mi*16 + quad*4 + r4;
      #pragma unroll
      for (int ni=0;ni<4;ni++){
        int col = wcol + ni*16 + l15;
        As[row*128 + ((((col>>3) ^ (row&15))<<3)) + (col&7)] = f2b(acc[mi][ni][r4]);
      }
    }
  }
  __syncthreads();
  const float scale = 0.17677669529663689f;
  for (int pid = t; pid < 512; pid += 256){
    int le = pid>>2, h = pid&3;
    int e = ebase + le;
    if (e >= NE) continue;
    int s = srcs[e], d = dsts[e];
    float dot = 0.f;
    #pragma unroll
    for (int j4=0;j4<4;j4++){
      int off = h*32 + j4*8;
      U4 qv, kv, ev;
      qv.v = *(const uint4*)(q + (size_t)d*DD + off);
      kv.v = *(const uint4*)(k + (size_t)s*DD + off);
      ev.v = *(const uint4*)(As + le*128 + ((((h*4+j4) ^ (le&15))<<3)));
      #pragma unroll
      for (int j=0;j<8;j++) dot += b2f(qv.s[j]) * (b2f(kv.s[j]) + b2f(ev.s[j]));
    }
    sc[(size_t)e*4 + h] = dot * scale;
  }
}

// ---------- per-node softmax + aggregation over sorted CSR ----------
__global__ __launch_bounds__(256,2) void nodeagg_k(
    const float* __restrict__ sc, const u16* __restrict__ v,
    const u16* __restrict__ E, const int* __restrict__ srcs,
    const int* __restrict__ offs, const u16* __restrict__ WevL,
    u16* __restrict__ agg)
{
  __shared__ float sh[16*4*129];
  int t = threadIdx.x;
  int node = blockIdx.x*16 + (t>>4);
  int sub = t & 15, h = sub>>2, p4 = sub&3;
  float uh[32];
  #pragma unroll
  for (int j=0;j<32;j++) uh[j]=0.f;
  float accv[8] = {0.f,0.f,0.f,0.f,0.f,0.f,0.f,0.f};
  int beg = 0, end = 0;
  if (node < NN){ beg = offs[node]; end = offs[node+1]; }
  float m = -1e30f, den = 0.f;
  for (int i=beg;i<end;i++){
    float s = sc[(size_t)i*4 + h];
    float mn = fmaxf(m, s);
    den = den*__expf(m-mn) + __expf(s-mn);
    m = mn;
  }
  float inv = 1.0f/(den + 1e-16f);
  int offv = h*32 + p4*8;
  for (int i=beg;i<end;i++){
    float a = __expf(sc[(size_t)i*4 + h] - m)*inv;
    U4 vv; vv.v = *(const uint4*)(v + (size_t)srcs[i]*DD + offv);
    #pragma unroll
    for (int j=0;j<8;j++) accv[j] += a*b2f(vv.s[j]);
    const u16* er = E + (size_t)i*DD + p4*32;
    #pragma unroll
    for (int qq=0;qq<4;qq++){
      U4 ee; ee.v = *(const uint4*)(er + qq*8);
      #pragma unroll
      for (int j=0;j<8;j++) uh[qq*8+j] += a*b2f(ee.s[j]);
    }
  }
  int base = ((t>>4)*4 + h)*129;
  #pragma unroll
  for (int j=0;j<32;j++) sh[base + p4*32 + j] = uh[j];
  __syncthreads();
  if (node >= NN) return;
  float o8[8];
  #pragma unroll
  for (int j=0;j<8;j++) o8[j] = accv[j];
  for (int kk=0;kk<128;kk+=4){
    float u0 = sh[base+kk], u1 = sh[base+kk+1], u2 = sh[base+kk+2], u3 = sh[base+kk+3];
    U4 w0,w1,w2,w3;
    w0.v = *(const uint4*)(WevL + (size_t)kk*DD + offv);
    w1.v = *(const uint4*)(WevL + (size_t)(kk+1)*DD + offv);
    w2.v = *(const uint4*)(WevL + (size_t)(kk+2)*DD + offv);
    w3.v = *(const uint4*)(WevL + (size_t)(kk+3)*DD + offv);
    #pragma unroll
    for (int j=0;j<8;j++)
      o8[j] += u0*b2f(w0.s[j]) + u1*b2f(w1.s[j]) + u2*b2f(w2.s[j]) + u3*b2f(w3.s[j]);
  }
  U4 o;
  #pragma unroll
  for (int j=0;j<8;j++) o.s[j] = f2b(o8[j]);
  *(uint4*)(agg + (size_t)node*DD + offv) = o.v;
}

// ---------- pooling: counting sort by graph, then segmented register sums ----------
__global__ void hist_k(const int* __restrict__ gid, const int* __restrict__ mask, int n,
                       int* __restrict__ hist){
  __shared__ int lh[NG];
  int t = threadIdx.x;
  if (t < NG) lh[t]=0;
  __syncthreads();
  int i = blockIdx.x*256 + t;
  if (i < n && (!mask || mask[i]==0)) atomicAdd(&lh[gid[i]], 1);
  __syncthreads();
  if (t < NG && lh[t]) atomicAdd(&hist[t], lh[t]);
}
__global__ void scan64_k(const int* __restrict__ hist, int* __restrict__ base, int* __restrict__ cur){
  if (threadIdx.x==0){
    int a=0;
    for (int g=0; g<NG; g++){ base[g]=a; cur[g]=a; a+=hist[g]; }
    base[NG]=a;
  }
}
__global__ void fillperm_k(const int* __restrict__ gid, const int* __restrict__ mask, int n,
                           int* __restrict__ cur, int* __restrict__ operm){
  __shared__ int lh[NG];
  __shared__ int lb[NG];
  int t = threadIdx.x;
  if (t < NG) lh[t]=0;
  __syncthreads();
  int i = blockIdx.x*256 + t;
  int g=-1, r=0;
  if (i < n && (!mask || mask[i]==0)){ g = gid[i]; r = atomicAdd(&lh[g], 1); }
  __syncthreads();
  if (t < NG && lh[t]) lb[t] = atomicAdd(&cur[t], lh[t]);
  __syncthreads();
  if (g >= 0) operm[lb[g] + r] = i;
}
__global__ __launch_bounds__(256,4) void poolsum_k(
    const u16* __restrict__ feat, const int* __restrict__ operm,
    const int* __restrict__ base, int chunks, float* __restrict__ outsum)
{
  __shared__ float sh[16*128];
  int g = blockIdx.x / chunks, c = blockIdx.x % chunks;
  int beg = base[g], end = base[g+1];
  int len = end - beg;
  int cb = beg + (int)(((long long)len*c)/chunks);
  int ce = beg + (int)(((long long)len*(c+1))/chunks);
  int t = threadIdx.x, grp = t>>4, sub = t&15;
  float acc[8] = {0.f,0.f,0.f,0.f,0.f,0.f,0.f,0.f};
  for (int i = cb+grp; i < ce; i += 16){
    int r = operm[i];
    U4 fv; fv.v = *(const uint4*)(feat + (size_t)r*DD + sub*8);
    #pragma unroll
    for (int j=0;j<8;j++) acc[j] += b2f(fv.s[j]);
  }
  #pragma unroll
  for (int j=0;j<8;j++) sh[grp*128 + sub*8 + j] = acc[j];
  __syncthreads();
  if (t < 128){
    float s = 0.f;
    #pragma unroll
    for (int r=0;r<16;r++) s += sh[r*128 + t];
    if (s != 0.f) atomicAdd(&outsum[g*DD + t], s);
  }
}

__global__ void ganorm_k(const float* __restrict__ gsum, const int* __restrict__ ncnt,
                         const float* __restrict__ esum, const int* __restrict__ ecnt,
                         float* __restrict__ ga){
  int id = blockIdx.x*256 + threadIdx.x;
  if (id >= NG*256) return;
  int g = id>>8, c = id&255;
  float v;
  if (c < 128) v = gsum[g*DD + c] / fmaxf((float)ncnt[g], 1.f);
  else         v = esum[g*DD + (c-128)] / fmaxf((float)ecnt[g], 1.f);
  ga[(size_t)g*256 + c] = v;
}

__global__ void mlp1_k(const float* __restrict__ ga, const u16* __restrict__ QW1,
                       const u16* __restrict__ Qb1, float* __restrict__ h){
  int o = blockIdx.x*256 + threadIdx.x;
  if (o >= NG*DD) return;
  int g = o>>7, j = o&127;
  float s = b2f(Qb1[j]);
  #pragma unroll 4
  for (int kq=0;kq<256;kq++) s += ga[(size_t)g*256 + kq] * b2f(QW1[(size_t)kq*DD + j]);
  h[o] = fmaxf(s, 0.f);
}

__global__ __launch_bounds__(128) void mlp2_k(const float* __restrict__ h, const u16* __restrict__ QW2,
                       const u16* __restrict__ Qb2, void* __restrict__ out, const int* __restrict__ flags){
  __shared__ float lsh[NA];
  __shared__ float red[128];
  int g = blockIdx.x, t = threadIdx.x;
  float s = -1e30f;
  if (t < NA){
    float acc = b2f(Qb2[t]);
    #pragma unroll 4
    for (int kq=0;kq<DD;kq++) acc += h[(size_t)g*DD + kq] * b2f(QW2[(size_t)kq*NA + t]);
    lsh[t] = acc; s = acc;
  }
  red[t] = s; __syncthreads();
  for (int d=64; d>0; d>>=1){ if (t<d) red[t] = fmaxf(red[t], red[t+d]); __syncthreads(); }
  float m = red[0]; __syncthreads();
  float ex = (t < NA) ? __expf(lsh[t]-m) : 0.f;
  red[t] = ex; __syncthreads();
  for (int d=64; d>0; d>>=1){ if (t<d) red[t] += red[t+d]; __syncthreads(); }
  float lse = m + __logf(red[0]);
  if (t < NA){
    float r = lsh[t]-lse;
    if (flags[0]) ((float*)out)[(size_t)g*NA + t] = r;
    else          ((u16*)out)[(size_t)g*NA + t]  = f2b(r);
  }
}

extern "C" void kernel_launch(void* const* d_in, const int* in_sizes, int n_in,
                              void* d_out, int out_size, void* d_ws, size_t ws_size,
                              hipStream_t stream) {
  (void)in_sizes; (void)n_in;
  const int* x      = (const int*)d_in[0];
  const int* ntype  = (const int*)d_in[1];
  const int* batch  = (const int*)d_in[2];
  const int* eidx   = (const int*)d_in[3];
  const int* src    = eidx;
  const int* dstp   = eidx + NE;
  const int* flow   = (const int*)d_in[4];
  const int* pos    = (const int*)d_in[5];
  const int* blk    = (const int*)d_in[6];

  char* p = (char*)d_ws;
  auto alloc = [&](size_t bytes)->char* {
    char* r = p; p += (bytes + 255) & ~(size_t)255; return r;
  };
  u16* embB  = (u16*)alloc((size_t)8192*DD*2);
  u16* flowB = (u16*)alloc(8*DD*2);
  u16* posB  = (u16*)alloc(64*DD*2);
  u16* blkB  = (u16*)alloc(2*DD*2);
  const size_t WSZb = (size_t)NL*DD*DD*2;
  u16* WevB = (u16*)alloc(WSZb);
  u16* QW1B = (u16*)alloc((size_t)256*DD*2);
  u16* Qb1B = (u16*)alloc(DD*2);
  u16* QW2B = (u16*)alloc((size_t)DD*NA*2);
  u16* Qb2B = (u16*)alloc(NA*2);
  u16* WqT  = (u16*)alloc(WSZb);
  u16* WkT  = (u16*)alloc(WSZb);
  u16* WvT  = (u16*)alloc(WSZb);
  u16* WekT = (u16*)alloc(WSZb);
  u16* WoT  = (u16*)alloc(WSZb);
  u16* WeuT = (u16*)alloc((size_t)NL*DD*384*2);
  const size_t NB = (size_t)NN*DD*2;
  u16* A  = (u16*)alloc(NB);
  u16* QB = (u16*)alloc(NB);
  u16* KB = (u16*)alloc(NB);     // k, then v
  u16* SCRATCH = (u16*)alloc(NB);  // hosts init-only / pool-only int arrays
  const size_t EB = (size_t)NE*DD*2;
  u16* E = (u16*)alloc(EB);
  float* scores = (float*)alloc((size_t)NE*4*4);
  int* srcs   = (int*)alloc((size_t)NE*4);
  int* dsts   = (int*)alloc((size_t)NE*4);
  int* ebgs   = (int*)alloc((size_t)NE*4);
  int* offs   = (int*)alloc((size_t)(NN+1)*4);
  float* gsum = (float*)alloc((size_t)NG*DD*4);
  float* esum = (float*)alloc((size_t)NG*DD*4);
  float* ga = (float*)alloc((size_t)NG*256*4);
  float* h  = (float*)alloc((size_t)NG*DD*4);
  int* flags = (int*)alloc(16);   // [0]=isf32 [2]=detect count

  // sub-allocations inside SCRATCH (init-only / pool-only lifetimes):
  char* q = (char*)SCRATCH;
  auto suballoc = [&](size_t bytes)->char* {
    char* r = q; q += (bytes + 255) & ~(size_t)255; return r;
  };
  int* perm   = (int*)suballoc((size_t)NE*4);     // init-only
  int* cnt    = (int*)suballoc((size_t)NN*4);     // init-only
  int* excl   = (int*)suballoc((size_t)NN*4);     // init-only
  int* bsum   = (int*)suballoc(1024*4);           // init-only
  int* cursor = (int*)suballoc((size_t)NN*4);     // init-only
  int* eperm  = (int*)suballoc((size_t)NE*4);     // pool-only
  int* nperm  = (int*)suballoc((size_t)NN*4);     // pool-only
  int* ehist  = (int*)suballoc(NG*4);
  int* ebase  = (int*)suballoc((NG+1)*4);
  int* ecur   = (int*)suballoc(NG*4);
  int* nhist  = (int*)suballoc(NG*4);
  int* nbase  = (int*)suballoc((NG+1)*4);
  int* ncur   = (int*)suballoc(NG*4);

  size_t needed = (size_t)(p - (char*)d_ws);
  if (needed > ws_size){
    diag_k<<<(out_size+255)/256,256,0,stream>>>((u16*)d_out, out_size, (float)(ws_size>>20));
    return;
  }

  // --- dtype detection + param conversion (+fused transpose) ---
  zero_k<<<1,256,0,stream>>>(flags, 4);
  detect_k<<<(DET_PAIRS+255)/256,256,0,stream>>>((const u16*)d_in[8], flags);
  flagset_k<<<1,64,0,stream>>>(flags);
  auto conv = [&](int idx, u16* dst, int n){
    tobf16_k<<<(n+255)/256,256,0,stream>>>(d_in[idx], dst, n, flags);
  };
  auto convT = [&](int idx, u16* dst, int L, int K, int Nc){
    int n = L*K*Nc;
    convT_k<<<(n+255)/256,256,0,stream>>>(d_in[idx], dst, L, K, Nc, flags);
  };
  conv(8,  embB,  8192*DD);
  conv(9,  flowB, 8*DD);
  conv(10, posB,  64*DD);
  conv(11, blkB,  2*DD);
  convT(12, WqT,  NL, DD, DD);
  convT(13, WkT,  NL, DD, DD);
  convT(14, WvT,  NL, DD, DD);
  convT(15, WekT, NL, DD, DD);
  conv(16, WevB, NL*DD*DD);
  convT(17, WoT,  NL, DD, DD);
  convT(18, WeuT, NL, 384, DD);
  conv(19, QW1B, 256*DD);
  conv(20, Qb1B, DD);
  conv(21, QW2B, DD*NA);
  conv(22, Qb2B, NA);

  // --- CSR over dst, sorted edge arrays, init ---
  zero_k<<<(NN+255)/256,256,0,stream>>>(cnt, NN);
  count_k<<<(NE+255)/256,256,0,stream>>>(dstp, cnt);
  int nb = (NN+255)/256;
  scan1_k<<<nb,256,0,stream>>>(cnt, excl, bsum, NN);
  scan2_k<<<1,64,0,stream>>>(bsum, nb);
  scan3_k<<<nb,256,0,stream>>>(excl, bsum, offs, cursor, NN, NE);
  fill_k<<<(NE+255)/256,256,0,stream>>>(dstp, cursor, perm);
  make_sorted_k<<<(NE+255)/256,256,0,stream>>>(perm, src, dstp, srcs, dsts);
  featinit_k<<<(NN*16+255)/256,256,0,stream>>>(x, embB, A);
  edgeinit_k<<<(NE*16+255)/256,256,0,stream>>>(perm, flow, pos, blk, srcs, dsts, batch,
                                               flowB, posB, blkB, E, ebgs);

  // --- layers ---
  dim3 gN((NN+127)/128), gE((NE+127)/128);
  for (int l=0; l<NL; l++){
    const u16* wq  = WqT  + (size_t)l*DD*DD;
    const u16* wk  = WkT  + (size_t)l*DD*DD;
    const u16* wv  = WvT  + (size_t)l*DD*DD;
    const u16* wek = WekT + (size_t)l*DD*DD;
    const u16* wo  = WoT  + (size_t)l*DD*DD;
    const u16* wevL= WevB + (size_t)l*DD*DD;
    const u16* weu = WeuT + (size_t)l*DD*384;

    gemm_k<<<gN,256,0,stream>>>(A,nullptr,nullptr,nullptr,nullptr,nullptr,1, wq,128, nullptr,0, QB, NN);
    gemm_k<<<gN,256,0,stream>>>(A,nullptr,nullptr,nullptr,nullptr,nullptr,1, wk,128, nullptr,0, KB, NN);
    scores_fused_k<<<gE,256,0,stream>>>(E, wek, QB, KB, srcs, dsts, scores);
    gemm_k<<<gN,256,0,stream>>>(A,nullptr,nullptr,nullptr,nullptr,nullptr,1, wv,128, nullptr,0, KB, NN);
    nodeagg_k<<<(NN+15)/16,256,0,stream>>>(scores, KB, E, srcs, offs, wevL, QB);
    // E = relu(E + [A[src], A[dst], E] @ Weu)  (3-chunk gather staging, in-place)
    gemm_k<<<gE,256,0,stream>>>(A,srcs, A,dsts, E,nullptr, 3, weu,384, E,1, E, NE);
    // A = relu(A + agg @ Wo)
    gemm_k<<<gN,256,0,stream>>>(QB,nullptr,nullptr,nullptr,nullptr,nullptr,1, wo,128, A,1, A, NN);
  }

  // --- pooling: counting sort by graph + segmented sums ---
  zero_k<<<1,256,0,stream>>>(ehist, NG);
  zero_k<<<1,256,0,stream>>>(nhist, NG);
  zero_k<<<(NG*DD+255)/256,256,0,stream>>>((int*)gsum, NG*DD);
  zero_k<<<(NG*DD+255)/256,256,0,stream>>>((int*)esum, NG*DD);
  hist_k<<<(NE+255)/256,256,0,stream>>>(ebgs, nullptr, NE, ehist);
  hist_k<<<(NN+255)/256,256,0,stream>>>(batch, ntype, NN, nhist);
  scan64_k<<<1,64,0,stream>>>(ehist, ebase, ecur);
  scan64_k<<<1,64,0,stream>>>(nhist, nbase, ncur);
  fillperm_k<<<(NE+255)/256,256,0,stream>>>(ebgs, nullptr, NE, ecur, eperm);
  fillperm_k<<<(NN+255)/256,256,0,stream>>>(batch, ntype, NN, ncur, nperm);
  const int ECH = 16, NCH = 4;
  poolsum_k<<<NG*ECH,256,0,stream>>>(E, eperm, ebase, ECH, esum);
  poolsum_k<<<NG*NCH,256,0,stream>>>(A, nperm, nbase, NCH, gsum);
  ganorm_k<<<(NG*256+255)/256,256,0,stream>>>(gsum, nhist, esum, ehist, ga);
  mlp1_k<<<(NG*DD+255)/256,256,0,stream>>>(ga, QW1B, Qb1B, h);
  mlp2_k<<<NG,128,0,stream>>>(h, QW2B, Qb2B, d_out, flags);
}

// Round 10
// 4543.628 us; speedup vs baseline: 1.2962x; 1.0302x over previous
//
#include <hip/hip_runtime.h>
#include <stdint.h>

#define NN 100000
#define NE 500000
#define DD 128
#define NL 8
#define NG 64
#define NA 100
#define DET_PAIRS 65536

typedef unsigned short u16;
typedef unsigned int u32;
typedef __attribute__((ext_vector_type(8))) short short8;
typedef __attribute__((ext_vector_type(4))) float f32x4;

union U4 { uint4 v; u16 s[8]; };

__device__ __forceinline__ float b2f(u16 u){ union{u32 i; float f;} x; x.i=((u32)u)<<16; return x.f; }
__device__ __forceinline__ u16 f2b(float f){ union{float f; u32 i;} x; x.f=f; u32 b=x.i; b += 0x7fffu + ((b>>16)&1u); return (u16)(b>>16); }

__global__ void zero_k(int* __restrict__ p, int n){
  int i = blockIdx.x*256 + threadIdx.x;
  if (i < n) p[i] = 0;
}
__global__ void diag_k(u16* __restrict__ out, int n, float val){
  int i = blockIdx.x*256 + threadIdx.x;
  if (i < n) out[i] = f2b(val);
}

// ---------- dtype detection: fp32 vs bf16 params ----------
__global__ void detect_k(const u16* __restrict__ raw, int* __restrict__ flags){
  int i = blockIdx.x*256 + threadIdx.x;
  int ok = 0;
  if (i < DET_PAIRS){
    u16 v = raw[2*i];
    int e = (v>>7)&0xFF;
    ok = ((e >= 107 && e <= 147) || ((v & 0x7FFFu) == 0)) ? 1 : 0;
  }
  unsigned long long b = __ballot(ok);
  if ((threadIdx.x & 63) == 0) atomicAdd(&flags[2], (int)__popcll(b));
}
__global__ void flagset_k(int* __restrict__ flags){
  if (threadIdx.x==0) flags[0] = (flags[2] < DET_PAIRS/2) ? 1 : 0;
}
__global__ void tobf16_k(const void* __restrict__ in, u16* __restrict__ out, int n,
                         const int* __restrict__ flags){
  int i = blockIdx.x*256 + threadIdx.x;
  if (i >= n) return;
  if (flags[0]) out[i] = f2b(((const float*)in)[i]);
  else          out[i] = ((const u16*)in)[i];
}
// convert + transpose: out[l][n][k] = cast(in[l][k][n])
__global__ void convT_k(const void* __restrict__ in, u16* __restrict__ out, int L, int K, int Nn,
                        const int* __restrict__ flags){
  int id = blockIdx.x*256 + threadIdx.x;
  int tot = L*K*Nn;
  if (id >= tot) return;
  int l = id/(K*Nn); int r = id - l*K*Nn;
  int k = r/Nn; int n = r - k*Nn;
  u16 v;
  if (flags[0]) v = f2b(((const float*)in)[id]);
  else          v = ((const u16*)in)[id];
  out[(size_t)l*K*Nn + (size_t)n*K + k] = v;
}

// ---------- feat = emb_table[x] ----------
__global__ void featinit_k(const int* __restrict__ x, const u16* __restrict__ emb, u16* __restrict__ feat){
  int id = blockIdx.x*256 + threadIdx.x;
  if (id >= NN*16) return;
  int row = id>>4, c8 = (id&15)*8;
  int g = x[row];
  *(uint4*)(feat + (size_t)row*DD + c8) = *(const uint4*)(emb + (size_t)g*DD + c8);
}

// ---------- CSR over dst ----------
__global__ void count_k(const int* __restrict__ dst, int* __restrict__ cnt){
  int e = blockIdx.x*256 + threadIdx.x;
  if (e < NE) atomicAdd(&cnt[dst[e]], 1);
}
__global__ void scan1_k(const int* __restrict__ cnt, int* __restrict__ excl, int* __restrict__ bsum, int n){
  __shared__ int sh[256];
  int t = threadIdx.x, g = blockIdx.x*256 + t;
  int v = (g<n) ? cnt[g] : 0;
  sh[t] = v; __syncthreads();
  for (int d=1; d<256; d<<=1){
    int xv = (t>=d) ? sh[t-d] : 0;
    __syncthreads();
    sh[t] += xv;
    __syncthreads();
  }
  if (g<n) excl[g] = sh[t]-v;
  if (t==255) bsum[blockIdx.x] = sh[255];
}
__global__ void scan2_k(int* __restrict__ bsum, int nb){
  if (threadIdx.x==0 && blockIdx.x==0){
    int a=0;
    for (int i=0;i<nb;i++){ int x=bsum[i]; bsum[i]=a; a+=x; }
  }
}
__global__ void scan3_k(const int* __restrict__ excl, const int* __restrict__ bsum,
                        int* __restrict__ offs, int* __restrict__ cursor, int n, int total){
  int g = blockIdx.x*256 + threadIdx.x;
  if (g < n){ int o = excl[g] + bsum[g>>8]; offs[g]=o; cursor[g]=o; }
  if (g==0) offs[n] = total;
}
__global__ void fill_k(const int* __restrict__ dst, int* __restrict__ cursor, int* __restrict__ perm){
  int e = blockIdx.x*256 + threadIdx.x;
  if (e < NE){ int p = atomicAdd(&cursor[dst[e]], 1); perm[p] = e; }
}
__global__ void make_sorted_k(const int* __restrict__ perm, const int* __restrict__ src,
                              const int* __restrict__ dst, int* __restrict__ srcs, int* __restrict__ dsts){
  int i = blockIdx.x*256 + threadIdx.x;
  if (i < NE){ int ed = perm[i]; srcs[i] = src[ed]; dsts[i] = dst[ed]; }
}

// ---------- E (dst-sorted) init + ebg_s ----------
__global__ void edgeinit_k(const int* __restrict__ perm, const int* __restrict__ flow,
                           const int* __restrict__ pos, const int* __restrict__ blk,
                           const int* __restrict__ srcs, const int* __restrict__ dsts,
                           const int* __restrict__ batch,
                           const u16* __restrict__ flow_emb, const u16* __restrict__ pos_emb,
                           const u16* __restrict__ blk_emb,
                           u16* __restrict__ e, int* __restrict__ ebgs){
  int id = blockIdx.x*256 + threadIdx.x;
  if (id >= NE*16) return;
  int i = id>>4, c8 = (id&15)*8;
  int ed = perm[i];
  int s = srcs[i], d = dsts[i];
  int cross = (blk[s] != blk[d]) ? 1 : 0;
  U4 a,b,c,o;
  a.v = *(const uint4*)(flow_emb + (size_t)flow[ed]*DD + c8);
  b.v = *(const uint4*)(pos_emb  + (size_t)pos[ed]*DD + c8);
  c.v = *(const uint4*)(blk_emb  + (size_t)cross*DD + c8);
  #pragma unroll
  for (int j=0;j<8;j++) o.s[j] = f2b(b2f(a.s[j]) + b2f(b.s[j]) + b2f(c.s[j]));
  *(uint4*)(e + (size_t)i*DD + c8) = o.v;
  if ((id&15)==0) ebgs[i] = batch[s];
}

// ---------- GEMM: C = (relu)(res + sum_c A_c[gather]@B_c), B-frags direct from L2 ----------
// A staged in 32KB LDS (XOR-granule, conflict-free); B per-fragment from global.
// res_lds!=0: residual = LAST staged chunk, read from LDS (no global res re-read).
// Epilogue: acc -> LDS -> fully-coalesced uint4 stores.
__global__ __launch_bounds__(256,4) void gemm_k(
    const u16* A0, const int* __restrict__ i0,
    const u16* A1, const int* __restrict__ i1,
    const u16* A2, const int* __restrict__ i2, int nchunks,
    const u16* __restrict__ Bt, int Ktot,
    const u16* res, int do_relu, int res_lds,
    u16* C, int M)
{
  __shared__ u16 As[128*128];
  int t = threadIdx.x;
  int mbase = blockIdx.x*128;
  int lane = t & 63, w = t>>6;
  int wrow = (w>>1)*64, wcol = (w&1)*64;
  int rl_w = t>>4, gw = t&15;
  int l15 = lane & 15, quad = lane>>4;
  f32x4 acc[4][4];
  #pragma unroll
  for (int mi=0;mi<4;mi++)
    #pragma unroll
    for (int ni=0;ni<4;ni++){ acc[mi][ni][0]=0.f; acc[mi][ni][1]=0.f; acc[mi][ni][2]=0.f; acc[mi][ni][3]=0.f; }

  for (int c=0; c<nchunks; c++){
    const u16* A = (c==0)?A0:((c==1)?A1:A2);
    const int* idx = (c==0)?i0:((c==1)?i1:i2);
    if (c > 0) __syncthreads();
    #pragma unroll
    for (int i=0;i<8;i++){
      int gm = mbase + rl_w + 16*i;
      uint4 av = make_uint4(0u,0u,0u,0u);
      if (gm < M){
        size_t grow = idx ? (size_t)idx[gm] : (size_t)gm;
        av = *(const uint4*)(A + grow*DD + gw*8);
      }
      *(uint4*)(As + (size_t)(i*256 + rl_w*16 + (gw ^ rl_w))*8) = av;
    }
    __syncthreads();
    #pragma unroll
    for (int kk=0;kk<4;kk++){
      int kg = kk*4 + quad;
      short8 af[4], bfr[4];
      #pragma unroll
      for (int mi=0;mi<4;mi++)
        af[mi] = *(const short8*)(As + (size_t)(((wrow>>4)+mi)*256 + l15*16 + (kg ^ l15))*8);
      #pragma unroll
      for (int ni=0;ni<4;ni++)
        bfr[ni] = *(const short8*)(Bt + (size_t)(wcol + ni*16 + l15)*Ktot + c*128 + kg*8);
      #pragma unroll
      for (int mi=0;mi<4;mi++)
        #pragma unroll
        for (int ni=0;ni<4;ni++)
          acc[mi][ni] = __builtin_amdgcn_mfma_f32_16x16x32_bf16(af[mi], bfr[ni], acc[mi][ni], 0, 0, 0);
    }
  }

  // residual from LDS (last staged chunk still in As; reads only, no race)
  if (res_lds){
    #pragma unroll
    for (int mi=0;mi<4;mi++){
      #pragma unroll
      for (int r4=0;r4<4;r4++){
        int row = wrow + mi*16 + quad*4 + r4;
        #pragma unroll
        for (int ni=0;ni<4;ni++){
          int col = wcol + ni*16 + l15;
          float r = b2f(As[(row>>4)*2048 + (row&15)*128 + (((col>>3) ^ (row&15))<<3) + (col&7)]);
          float vv = acc[mi][ni][r4] + r;
          if (do_relu && vv < 0.f) vv = 0.f;
          acc[mi][ni][r4] = vv;
        }
      }
    }
  }
  __syncthreads();
  #pragma unroll
  for (int mi=0;mi<4;mi++){
    #pragma unroll
    for (int r4=0;r4<4;r4++){
      int row = wrow + mi*16 + quad*4 + r4;
      #pragma unroll
      for (int ni=0;ni<4;ni++){
        int col = wcol + ni*16 + l15;
        As[row*128 + ((((col>>3) ^ (row&15))<<3)) + (col&7)] = f2b(acc[mi][ni][r4]);
      }
    }
  }
  __syncthreads();
  #pragma unroll
  for (int i=0;i<8;i++){
    int row = rl_w + 16*i;
    int gm = mbase + row;
    if (gm >= M) continue;
    U4 av; av.v = *(const uint4*)(As + row*128 + ((gw ^ (row&15))<<3));
    if (res_lds){
      *(uint4*)(C + (size_t)gm*DD + gw*8) = av.v;   // residual+relu already applied
      continue;
    }
    float vals[8];
    #pragma unroll
    for (int j=0;j<8;j++) vals[j] = b2f(av.s[j]);
    if (res){
      U4 rv; rv.v = *(const uint4*)(res + (size_t)gm*DD + gw*8);
      #pragma unroll
      for (int j=0;j<8;j++) vals[j] += b2f(rv.s[j]);
    }
    U4 ov;
    #pragma unroll
    for (int j=0;j<8;j++){
      float v = vals[j];
      if (do_relu && v < 0.f) v = 0.f;
      ov.s[j] = f2b(v);
    }
    *(uint4*)(C + (size_t)gm*DD + gw*8) = ov.v;
  }
}

// ---------- fused: ek = E_tile @ Wek (MFMA, B direct), then scores ----------
__global__ __launch_bounds__(256,4) void scores_fused_k(
    const u16* __restrict__ E, const u16* __restrict__ WekT,
    const u16* __restrict__ q, const u16* __restrict__ k,
    const int* __restrict__ srcs, const int* __restrict__ dsts,
    float* __restrict__ sc)
{
  __shared__ u16 As[128*128];
  int t = threadIdx.x;
  int ebase = blockIdx.x*128;
  int lane = t & 63, w = t>>6;
  int wrow = (w>>1)*64, wcol = (w&1)*64;
  int rl_w = t>>4, gw = t&15;
  int l15 = lane & 15, quad = lane>>4;
  #pragma unroll
  for (int i=0;i<8;i++){
    int gm = ebase + rl_w + 16*i;
    uint4 av = make_uint4(0u,0u,0u,0u);
    if (gm < NE) av = *(const uint4*)(E + (size_t)gm*DD + gw*8);
    *(uint4*)(As + (size_t)(i*256 + rl_w*16 + (gw ^ rl_w))*8) = av;
  }
  __syncthreads();
  f32x4 acc[4][4];
  #pragma unroll
  for (int mi=0;mi<4;mi++)
    #pragma unroll
    for (int ni=0;ni<4;ni++){ acc[mi][ni][0]=0.f; acc[mi][ni][1]=0.f; acc[mi][ni][2]=0.f; acc[mi][ni][3]=0.f; }
  #pragma unroll
  for (int kk=0;kk<4;kk++){
    int kg = kk*4 + quad;
    short8 af[4], bfr[4];
    #pragma unroll
    for (int mi=0;mi<4;mi++)
      af[mi] = *(const short8*)(As + (size_t)(((wrow>>4)+mi)*256 + l15*16 + (kg ^ l15))*8);
    #pragma unroll
    for (int ni=0;ni<4;ni++)
      bfr[ni] = *(const short8*)(WekT + (size_t)(wcol + ni*16 + l15)*DD + kg*8);
    #pragma unroll
    for (int mi=0;mi<4;mi++)
      #pragma unroll
      for (int ni=0;ni<4;ni++)
        acc[mi][ni] = __builtin_amdgcn_mfma_f32_16x16x32_bf16(af[mi], bfr[ni], acc[mi][ni], 0, 0, 0);
  }
  __syncthreads();
  #pragma unroll
  for (int mi=0;mi<4;mi++){
    #pragma unroll
    for (int r4=0;r4<4;r4++){
      int row = wrow + mi*16 + quad*4 + r4;
      #pragma unroll
      for (int ni=0;ni<4;ni++){
        int col = wcol + ni*16 + l15;
        As[row*128 + ((((col>>3) ^ (row&15))<<3)) + (col&7)] = f2b(acc[mi][ni][r4]);
      }
    }
  }
  __syncthreads();
  const float scale = 0.17677669529663689f;
  for (int pid = t; pid < 512; pid += 256){
    int le = pid>>2, h = pid&3;
    int e = ebase + le;
    if (e >= NE) continue;
    int s = srcs[e], d = dsts[e];
    float dot = 0.f;
    #pragma unroll
    for (int j4=0;j4<4;j4++){
      int off = h*32 + j4*8;
      U4 qv, kv, ev;
      qv.v = *(const uint4*)(q + (size_t)d*DD + off);
      kv.v = *(const uint4*)(k + (size_t)s*DD + off);
      ev.v = *(const uint4*)(As + le*128 + ((((h*4+j4) ^ (le&15))<<3)));
      #pragma unroll
      for (int j=0;j<8;j++) dot += b2f(qv.s[j]) * (b2f(kv.s[j]) + b2f(ev.s[j]));
    }
    sc[(size_t)e*4 + h] = dot * scale;
  }
}

// ---------- per-node softmax + aggregation over sorted CSR ----------
// Each thread owns column slice sub*8..sub*8+8, reads E ONCE per edge, and
// accumulates uh for all 4 heads (alpha per head from one float4 scores load).
__global__ __launch_bounds__(256,2) void nodeagg_k(
    const float* __restrict__ sc, const u16* __restrict__ v,
    const u16* __restrict__ E, const int* __restrict__ srcs,
    const int* __restrict__ offs, const u16* __restrict__ WevL,
    u16* __restrict__ agg)
{
  __shared__ float sh[16*4*129];
  int t = threadIdx.x;
  int n16 = t>>4;
  int node = blockIdx.x*16 + n16;
  int sub = t & 15;
  int hown = sub>>2;
  int offc = sub*8;               // owned column slice (== old h*32+p4*8)
  int beg = 0, end = 0;
  if (node < NN){ beg = offs[node]; end = offs[node+1]; }
  float m[4] = {-1e30f,-1e30f,-1e30f,-1e30f};
  float den[4] = {0.f,0.f,0.f,0.f};
  for (int i=beg;i<end;i++){
    float4 s4 = *(const float4*)(sc + (size_t)i*4);
    float ss[4] = {s4.x, s4.y, s4.z, s4.w};
    #pragma unroll
    for (int h=0;h<4;h++){
      float mn = fmaxf(m[h], ss[h]);
      den[h] = den[h]*__expf(m[h]-mn) + __expf(ss[h]-mn);
      m[h] = mn;
    }
  }
  float inv[4];
  #pragma unroll
  for (int h=0;h<4;h++) inv[h] = 1.0f/(den[h] + 1e-16f);
  float uh[4][8];
  #pragma unroll
  for (int h=0;h<4;h++)
    #pragma unroll
    for (int j=0;j<8;j++) uh[h][j]=0.f;
  float accv[8] = {0.f,0.f,0.f,0.f,0.f,0.f,0.f,0.f};
  for (int i=beg;i<end;i++){
    float4 s4 = *(const float4*)(sc + (size_t)i*4);
    float al[4] = { __expf(s4.x-m[0])*inv[0], __expf(s4.y-m[1])*inv[1],
                    __expf(s4.z-m[2])*inv[2], __expf(s4.w-m[3])*inv[3] };
    U4 ee; ee.v = *(const uint4*)(E + (size_t)i*DD + offc);
    #pragma unroll
    for (int j=0;j<8;j++){
      float ev = b2f(ee.s[j]);
      #pragma unroll
      for (int h=0;h<4;h++) uh[h][j] += al[h]*ev;
    }
    U4 vv; vv.v = *(const uint4*)(v + (size_t)srcs[i]*DD + offc);
    #pragma unroll
    for (int j=0;j<8;j++) accv[j] += al[hown]*b2f(vv.s[j]);
  }
  #pragma unroll
  for (int h=0;h<4;h++)
    #pragma unroll
    for (int j=0;j<8;j++) sh[(n16*4 + h)*129 + offc + j] = uh[h][j];
  __syncthreads();
  if (node >= NN) return;
  float o8[8];
  #pragma unroll
  for (int j=0;j<8;j++) o8[j] = accv[j];
  int base = (n16*4 + hown)*129;
  for (int kk=0;kk<128;kk+=4){
    float u0 = sh[base+kk], u1 = sh[base+kk+1], u2 = sh[base+kk+2], u3 = sh[base+kk+3];
    U4 w0,w1,w2,w3;
    w0.v = *(const uint4*)(WevL + (size_t)kk*DD + offc);
    w1.v = *(const uint4*)(WevL + (size_t)(kk+1)*DD + offc);
    w2.v = *(const uint4*)(WevL + (size_t)(kk+2)*DD + offc);
    w3.v = *(const uint4*)(WevL + (size_t)(kk+3)*DD + offc);
    #pragma unroll
    for (int j=0;j<8;j++)
      o8[j] += u0*b2f(w0.s[j]) + u1*b2f(w1.s[j]) + u2*b2f(w2.s[j]) + u3*b2f(w3.s[j]);
  }
  U4 o;
  #pragma unroll
  for (int j=0;j<8;j++) o.s[j] = f2b(o8[j]);
  *(uint4*)(agg + (size_t)node*DD + offc) = o.v;
}

// ---------- pooling: counting sort by graph, then segmented register sums ----------
__global__ void hist_k(const int* __restrict__ gid, const int* __restrict__ mask, int n,
                       int* __restrict__ hist){
  __shared__ int lh[NG];
  int t = threadIdx.x;
  if (t < NG) lh[t]=0;
  __syncthreads();
  int i = blockIdx.x*256 + t;
  if (i < n && (!mask || mask[i]==0)) atomicAdd(&lh[gid[i]], 1);
  __syncthreads();
  if (t < NG && lh[t]) atomicAdd(&hist[t], lh[t]);
}
__global__ void scan64_k(const int* __restrict__ hist, int* __restrict__ base, int* __restrict__ cur){
  if (threadIdx.x==0){
    int a=0;
    for (int g=0; g<NG; g++){ base[g]=a; cur[g]=a; a+=hist[g]; }
    base[NG]=a;
  }
}
__global__ void fillperm_k(const int* __restrict__ gid, const int* __restrict__ mask, int n,
                           int* __restrict__ cur, int* __restrict__ operm){
  __shared__ int lh[NG];
  __shared__ int lb[NG];
  int t = threadIdx.x;
  if (t < NG) lh[t]=0;
  __syncthreads();
  int i = blockIdx.x*256 + t;
  int g=-1, r=0;
  if (i < n && (!mask || mask[i]==0)){ g = gid[i]; r = atomicAdd(&lh[g], 1); }
  __syncthreads();
  if (t < NG && lh[t]) lb[t] = atomicAdd(&cur[t], lh[t]);
  __syncthreads();
  if (g >= 0) operm[lb[g] + r] = i;
}
__global__ __launch_bounds__(256,4) void poolsum_k(
    const u16* __restrict__ feat, const int* __restrict__ operm,
    const int* __restrict__ base, int chunks, float* __restrict__ outsum)
{
  __shared__ float sh[16*128];
  int g = blockIdx.x / chunks, c = blockIdx.x % chunks;
  int beg = base[g], end = base[g+1];
  int len = end - beg;
  int cb = beg + (int)(((long long)len*c)/chunks);
  int ce = beg + (int)(((long long)len*(c+1))/chunks);
  int t = threadIdx.x, grp = t>>4, sub = t&15;
  float acc[8] = {0.f,0.f,0.f,0.f,0.f,0.f,0.f,0.f};
  for (int i = cb+grp; i < ce; i += 16){
    int r = operm[i];
    U4 fv; fv.v = *(const uint4*)(feat + (size_t)r*DD + sub*8);
    #pragma unroll
    for (int j=0;j<8;j++) acc[j] += b2f(fv.s[j]);
  }
  #pragma unroll
  for (int j=0;j<8;j++) sh[grp*128 + sub*8 + j] = acc[j];
  __syncthreads();
  if (t < 128){
    float s = 0.f;
    #pragma unroll
    for (int r=0;r<16;r++) s += sh[r*128 + t];
    if (s != 0.f) atomicAdd(&outsum[g*DD + t], s);
  }
}

__global__ void ganorm_k(const float* __restrict__ gsum, const int* __restrict__ ncnt,
                         const float* __restrict__ esum, const int* __restrict__ ecnt,
                         float* __restrict__ ga){
  int id = blockIdx.x*256 + threadIdx.x;
  if (id >= NG*256) return;
  int g = id>>8, c = id&255;
  float v;
  if (c < 128) v = gsum[g*DD + c] / fmaxf((float)ncnt[g], 1.f);
  else         v = esum[g*DD + (c-128)] / fmaxf((float)ecnt[g], 1.f);
  ga[(size_t)g*256 + c] = v;
}

__global__ void mlp1_k(const float* __restrict__ ga, const u16* __restrict__ QW1,
                       const u16* __restrict__ Qb1, float* __restrict__ h){
  int o = blockIdx.x*256 + threadIdx.x;
  if (o >= NG*DD) return;
  int g = o>>7, j = o&127;
  float s = b2f(Qb1[j]);
  #pragma unroll 4
  for (int kq=0;kq<256;kq++) s += ga[(size_t)g*256 + kq] * b2f(QW1[(size_t)kq*DD + j]);
  h[o] = fmaxf(s, 0.f);
}

__global__ __launch_bounds__(128) void mlp2_k(const float* __restrict__ h, const u16* __restrict__ QW2,
                       const u16* __restrict__ Qb2, void* __restrict__ out, const int* __restrict__ flags){
  __shared__ float lsh[NA];
  __shared__ float red[128];
  int g = blockIdx.x, t = threadIdx.x;
  float s = -1e30f;
  if (t < NA){
    float acc = b2f(Qb2[t]);
    #pragma unroll 4
    for (int kq=0;kq<DD;kq++) acc += h[(size_t)g*DD + kq] * b2f(QW2[(size_t)kq*NA + t]);
    lsh[t] = acc; s = acc;
  }
  red[t] = s; __syncthreads();
  for (int d=64; d>0; d>>=1){ if (t<d) red[t] = fmaxf(red[t], red[t+d]); __syncthreads(); }
  float m = red[0]; __syncthreads();
  float ex = (t < NA) ? __expf(lsh[t]-m) : 0.f;
  red[t] = ex; __syncthreads();
  for (int d=64; d>0; d>>=1){ if (t<d) red[t] += red[t+d]; __syncthreads(); }
  float lse = m + __logf(red[0]);
  if (t < NA){
    float r = lsh[t]-lse;
    if (flags[0]) ((float*)out)[(size_t)g*NA + t] = r;
    else          ((u16*)out)[(size_t)g*NA + t]  = f2b(r);
  }
}

extern "C" void kernel_launch(void* const* d_in, const int* in_sizes, int n_in,
                              void* d_out, int out_size, void* d_ws, size_t ws_size,
                              hipStream_t stream) {
  (void)in_sizes; (void)n_in;
  const int* x      = (const int*)d_in[0];
  const int* ntype  = (const int*)d_in[1];
  const int* batch  = (const int*)d_in[2];
  const int* eidx   = (const int*)d_in[3];
  const int* src    = eidx;
  const int* dstp   = eidx + NE;
  const int* flow   = (const int*)d_in[4];
  const int* pos    = (const int*)d_in[5];
  const int* blk    = (const int*)d_in[6];

  char* p = (char*)d_ws;
  auto alloc = [&](size_t bytes)->char* {
    char* r = p; p += (bytes + 255) & ~(size_t)255; return r;
  };
  u16* embB  = (u16*)alloc((size_t)8192*DD*2);
  u16* flowB = (u16*)alloc(8*DD*2);
  u16* posB  = (u16*)alloc(64*DD*2);
  u16* blkB  = (u16*)alloc(2*DD*2);
  const size_t WSZb = (size_t)NL*DD*DD*2;
  u16* WevB = (u16*)alloc(WSZb);
  u16* QW1B = (u16*)alloc((size_t)256*DD*2);
  u16* Qb1B = (u16*)alloc(DD*2);
  u16* QW2B = (u16*)alloc((size_t)DD*NA*2);
  u16* Qb2B = (u16*)alloc(NA*2);
  u16* WqT  = (u16*)alloc(WSZb);
  u16* WkT  = (u16*)alloc(WSZb);
  u16* WvT  = (u16*)alloc(WSZb);
  u16* WekT = (u16*)alloc(WSZb);
  u16* WoT  = (u16*)alloc(WSZb);
  u16* WeuT = (u16*)alloc((size_t)NL*DD*384*2);
  const size_t NB = (size_t)NN*DD*2;
  u16* A  = (u16*)alloc(NB);
  u16* QB = (u16*)alloc(NB);
  u16* KB = (u16*)alloc(NB);     // k, then v
  u16* SCRATCH = (u16*)alloc(NB);  // hosts init-only / pool-only int arrays
  const size_t EB = (size_t)NE*DD*2;
  u16* E = (u16*)alloc(EB);
  float* scores = (float*)alloc((size_t)NE*4*4);
  int* srcs   = (int*)alloc((size_t)NE*4);
  int* dsts   = (int*)alloc((size_t)NE*4);
  int* ebgs   = (int*)alloc((size_t)NE*4);
  int* offs   = (int*)alloc((size_t)(NN+1)*4);
  float* gsum = (float*)alloc((size_t)NG*DD*4);
  float* esum = (float*)alloc((size_t)NG*DD*4);
  float* ga = (float*)alloc((size_t)NG*256*4);
  float* h  = (float*)alloc((size_t)NG*DD*4);
  int* flags = (int*)alloc(16);   // [0]=isf32 [2]=detect count

  // sub-allocations inside SCRATCH (init-only / pool-only lifetimes):
  char* q = (char*)SCRATCH;
  auto suballoc = [&](size_t bytes)->char* {
    char* r = q; q += (bytes + 255) & ~(size_t)255; return r;
  };
  int* perm   = (int*)suballoc((size_t)NE*4);     // init-only
  int* cnt    = (int*)suballoc((size_t)NN*4);     // init-only
  int* excl   = (int*)suballoc((size_t)NN*4);     // init-only
  int* bsum   = (int*)suballoc(1024*4);           // init-only
  int* cursor = (int*)suballoc((size_t)NN*4);     // init-only
  int* eperm  = (int*)suballoc((size_t)NE*4);     // pool-only
  int* nperm  = (int*)suballoc((size_t)NN*4);     // pool-only
  int* ehist  = (int*)suballoc(NG*4);
  int* ebase  = (int*)suballoc((NG+1)*4);
  int* ecur   = (int*)suballoc(NG*4);
  int* nhist  = (int*)suballoc(NG*4);
  int* nbase  = (int*)suballoc((NG+1)*4);
  int* ncur   = (int*)suballoc(NG*4);

  size_t needed = (size_t)(p - (char*)d_ws);
  if (needed > ws_size){
    diag_k<<<(out_size+255)/256,256,0,stream>>>((u16*)d_out, out_size, (float)(ws_size>>20));
    return;
  }

  // --- dtype detection + param conversion (+fused transpose) ---
  zero_k<<<1,256,0,stream>>>(flags, 4);
  detect_k<<<(DET_PAIRS+255)/256,256,0,stream>>>((const u16*)d_in[8], flags);
  flagset_k<<<1,64,0,stream>>>(flags);
  auto conv = [&](int idx, u16* dst, int n){
    tobf16_k<<<(n+255)/256,256,0,stream>>>(d_in[idx], dst, n, flags);
  };
  auto convT = [&](int idx, u16* dst, int L, int K, int Nc){
    int n = L*K*Nc;
    convT_k<<<(n+255)/256,256,0,stream>>>(d_in[idx], dst, L, K, Nc, flags);
  };
  conv(8,  embB,  8192*DD);
  conv(9,  flowB, 8*DD);
  conv(10, posB,  64*DD);
  conv(11, blkB,  2*DD);
  convT(12, WqT,  NL, DD, DD);
  convT(13, WkT,  NL, DD, DD);
  convT(14, WvT,  NL, DD, DD);
  convT(15, WekT, NL, DD, DD);
  conv(16, WevB, NL*DD*DD);
  convT(17, WoT,  NL, DD, DD);
  convT(18, WeuT, NL, 384, DD);
  conv(19, QW1B, 256*DD);
  conv(20, Qb1B, DD);
  conv(21, QW2B, DD*NA);
  conv(22, Qb2B, NA);

  // --- CSR over dst, sorted edge arrays, init ---
  zero_k<<<(NN+255)/256,256,0,stream>>>(cnt, NN);
  count_k<<<(NE+255)/256,256,0,stream>>>(dstp, cnt);
  int nb = (NN+255)/256;
  scan1_k<<<nb,256,0,stream>>>(cnt, excl, bsum, NN);
  scan2_k<<<1,64,0,stream>>>(bsum, nb);
  scan3_k<<<nb,256,0,stream>>>(excl, bsum, offs, cursor, NN, NE);
  fill_k<<<(NE+255)/256,256,0,stream>>>(dstp, cursor, perm);
  make_sorted_k<<<(NE+255)/256,256,0,stream>>>(perm, src, dstp, srcs, dsts);
  featinit_k<<<(NN*16+255)/256,256,0,stream>>>(x, embB, A);
  edgeinit_k<<<(NE*16+255)/256,256,0,stream>>>(perm, flow, pos, blk, srcs, dsts, batch,
                                               flowB, posB, blkB, E, ebgs);

  // --- layers ---
  dim3 gN((NN+127)/128), gE((NE+127)/128);
  for (int l=0; l<NL; l++){
    const u16* wq  = WqT  + (size_t)l*DD*DD;
    const u16* wk  = WkT  + (size_t)l*DD*DD;
    const u16* wv  = WvT  + (size_t)l*DD*DD;
    const u16* wek = WekT + (size_t)l*DD*DD;
    const u16* wo  = WoT  + (size_t)l*DD*DD;
    const u16* wevL= WevB + (size_t)l*DD*DD;
    const u16* weu = WeuT + (size_t)l*DD*384;

    gemm_k<<<gN,256,0,stream>>>(A,nullptr,nullptr,nullptr,nullptr,nullptr,1, wq,128, nullptr,0,0, QB, NN);
    gemm_k<<<gN,256,0,stream>>>(A,nullptr,nullptr,nullptr,nullptr,nullptr,1, wk,128, nullptr,0,0, KB, NN);
    scores_fused_k<<<gE,256,0,stream>>>(E, wek, QB, KB, srcs, dsts, scores);
    gemm_k<<<gN,256,0,stream>>>(A,nullptr,nullptr,nullptr,nullptr,nullptr,1, wv,128, nullptr,0,0, KB, NN);
    nodeagg_k<<<(NN+15)/16,256,0,stream>>>(scores, KB, E, srcs, offs, wevL, QB);
    // E = relu(E + [A[src], A[dst], E] @ Weu)  (residual = staged chunk 2, from LDS)
    gemm_k<<<gE,256,0,stream>>>(A,srcs, A,dsts, E,nullptr, 3, weu,384, nullptr,1,1, E, NE);
    // A = relu(A + agg @ Wo)  (global residual path)
    gemm_k<<<gN,256,0,stream>>>(QB,nullptr,nullptr,nullptr,nullptr,nullptr,1, wo,128, A,1,0, A, NN);
  }

  // --- pooling: counting sort by graph + segmented sums ---
  zero_k<<<1,256,0,stream>>>(ehist, NG);
  zero_k<<<1,256,0,stream>>>(nhist, NG);
  zero_k<<<(NG*DD+255)/256,256,0,stream>>>((int*)gsum, NG*DD);
  zero_k<<<(NG*DD+255)/256,256,0,stream>>>((int*)esum, NG*DD);
  hist_k<<<(NE+255)/256,256,0,stream>>>(ebgs, nullptr, NE, ehist);
  hist_k<<<(NN+255)/256,256,0,stream>>>(batch, ntype, NN, nhist);
  scan64_k<<<1,64,0,stream>>>(ehist, ebase, ecur);
  scan64_k<<<1,64,0,stream>>>(nhist, nbase, ncur);
  fillperm_k<<<(NE+255)/256,256,0,stream>>>(ebgs, nullptr, NE, ecur, eperm);
  fillperm_k<<<(NN+255)/256,256,0,stream>>>(batch, ntype, NN, ncur, nperm);
  const int ECH = 16, NCH = 4;
  poolsum_k<<<NG*ECH,256,0,stream>>>(E, eperm, ebase, ECH, esum);
  poolsum_k<<<NG*NCH,256,0,stream>>>(A, nperm, nbase, NCH, gsum);
  ganorm_k<<<(NG*256+255)/256,256,0,stream>>>(gsum, nhist, esum, ehist, ga);
  mlp1_k<<<(NG*DD+255)/256,256,0,stream>>>(ga, QW1B, Qb1B, h);
  mlp2_k<<<NG,128,0,stream>>>(h, QW2B, Qb2B, d_out, flags);
}